// Round 1
// baseline (7319.587 us; speedup 1.0000x reference)
//
#include <hip/hip_runtime.h>

// ---------------------------------------------------------------------------
// SemmaRelModel: two 6-layer NBFNet branches + MLP fusion.
// D = 64 fixed. One wave (64 lanes) owns one node-row for all dense math.
// Struct-branch state x_s lives in d_out (fusion is per-row in-place).
// Text branch is identical across batch -> computed once at [N,64].
// ---------------------------------------------------------------------------

#define WAVE 64

// x[idx] = (n == h_index[b]) ? 1 : 0   over [B,N,64]
__global__ __launch_bounds__(256) void k_init_onehot(
    float* __restrict__ x, const int* __restrict__ h_index, int N, int total)
{
    int idx = blockIdx.x * 256 + threadIdx.x;
    if (idx >= total) return;
    int row = idx >> 6;          // b*N + n
    int b = row / N;
    int n = row - b * N;
    x[idx] = (n == h_index[b]) ? 1.0f : 0.0f;
}

// agg[b, dst[e], :] += x[b, src[e], :] * rel[etype[e], :]
// one thread per (edge, float4-quad); loops over batch.
__global__ __launch_bounds__(256) void k_scatter(
    const float* __restrict__ x, float* __restrict__ agg,
    const int* __restrict__ src, const int* __restrict__ dst,
    const int* __restrict__ etype,        // may be null -> type 0
    const float* __restrict__ rel,        // [R,64]
    int E, int N, int Bn)
{
    int idx = blockIdx.x * 256 + threadIdx.x;
    if (idx >= E * 16) return;
    int e = idx >> 4;
    int q = idx & 15;
    int s = src[e];
    int t = dst[e];
    int ty = etype ? etype[e] : 0;
    const float4 r4 = *(const float4*)(rel + ty * 64 + q * 4);
    for (int b = 0; b < Bn; ++b) {
        const float4 xs = *(const float4*)(x + ((size_t)b * N + s) * 64 + q * 4);
        float* a = agg + ((size_t)b * N + t) * 64 + q * 4;
        unsafeAtomicAdd(a + 0, xs.x * r4.x);
        unsafeAtomicAdd(a + 1, xs.y * r4.y);
        unsafeAtomicAdd(a + 2, xs.z * r4.z);
        unsafeAtomicAdd(a + 3, xs.w * r4.w);
    }
}

// x_row = relu(LN(concat(x_row, agg_row) @ W + b)) + x_row   (in place)
// One wave per row. W (128x64 f32, 32KB) staged in LDS per block.
__global__ __launch_bounds__(256) void k_update(
    const float* __restrict__ W,      // [128,64] layer slice
    const float* __restrict__ bias,   // [64]
    const float* __restrict__ g,      // [64]
    const float* __restrict__ beta,   // [64]
    float* __restrict__ x,            // [rows,64] in/out
    const float* __restrict__ agg,    // [rows,64]
    int rows)
{
    __shared__ float Wl[128 * 64];
    __shared__ float bl[64], gl[64], betal[64];
    int tid = threadIdx.x;
    for (int i = tid; i < 128 * 64; i += 256) Wl[i] = W[i];
    if (tid < 64) { bl[tid] = bias[tid]; gl[tid] = g[tid]; betal[tid] = beta[tid]; }
    __syncthreads();

    int wave = tid >> 6;
    int lane = tid & 63;
    int wstride = gridDim.x * 4;
    for (int row = blockIdx.x * 4 + wave; row < rows; row += wstride) {
        float xv = x[(size_t)row * 64 + lane];
        float av = agg[(size_t)row * 64 + lane];
        float h = bl[lane];
        #pragma unroll
        for (int k = 0; k < 64; ++k)
            h += __shfl(xv, k) * Wl[k * 64 + lane];
        #pragma unroll
        for (int k = 0; k < 64; ++k)
            h += __shfl(av, k) * Wl[(64 + k) * 64 + lane];
        // LayerNorm across the 64 lanes
        float s = h;
        #pragma unroll
        for (int off = 32; off >= 1; off >>= 1) s += __shfl_xor(s, off);
        float m = s * (1.0f / 64.0f);
        float c = h - m;
        float v = c * c;
        #pragma unroll
        for (int off = 32; off >= 1; off >>= 1) v += __shfl_xor(v, off);
        v *= (1.0f / 64.0f);
        float y = c * rsqrtf(v + 1e-5f) * gl[lane] + betal[lane];
        y = fmaxf(y, 0.0f) + xv;
        x[(size_t)row * 64 + lane] = y;
    }
}

// out_row = relu(concat(h_row, z_row) @ W1 + b1) @ W2 + b2  (in place on out=h)
__global__ __launch_bounds__(256) void k_fuse(
    const float* __restrict__ W1, const float* __restrict__ b1,
    const float* __restrict__ W2, const float* __restrict__ b2,
    float* __restrict__ out,          // [B*N,64]: holds h, overwritten
    const float* __restrict__ z,      // [N,64]
    int N, int rows)
{
    __shared__ float W1l[128 * 64];
    __shared__ float W2l[64 * 64];
    __shared__ float b1l[64], b2l[64];
    int tid = threadIdx.x;
    for (int i = tid; i < 128 * 64; i += 256) W1l[i] = W1[i];
    for (int i = tid; i < 64 * 64; i += 256) W2l[i] = W2[i];
    if (tid < 64) { b1l[tid] = b1[tid]; b2l[tid] = b2[tid]; }
    __syncthreads();

    int wave = tid >> 6;
    int lane = tid & 63;
    int wstride = gridDim.x * 4;
    for (int row = blockIdx.x * 4 + wave; row < rows; row += wstride) {
        int n = row % N;
        float hv = out[(size_t)row * 64 + lane];
        float zv = z[(size_t)n * 64 + lane];
        float f = b1l[lane];
        #pragma unroll
        for (int k = 0; k < 64; ++k)
            f += __shfl(hv, k) * W1l[k * 64 + lane];
        #pragma unroll
        for (int k = 0; k < 64; ++k)
            f += __shfl(zv, k) * W1l[(64 + k) * 64 + lane];
        f = fmaxf(f, 0.0f);
        float o = b2l[lane];
        #pragma unroll
        for (int k = 0; k < 64; ++k)
            o += __shfl(f, k) * W2l[k * 64 + lane];
        out[(size_t)row * 64 + lane] = o;
    }
}

extern "C" void kernel_launch(void* const* d_in, const int* in_sizes, int n_in,
                              void* d_out, int out_size, void* d_ws, size_t ws_size,
                              hipStream_t stream)
{
    const float* rel_text_init = (const float*)d_in[0];
    const float* struct_rel    = (const float*)d_in[1];
    const float* struct_W      = (const float*)d_in[2];
    const float* struct_b      = (const float*)d_in[3];
    const float* struct_g      = (const float*)d_in[4];
    const float* struct_beta   = (const float*)d_in[5];
    const float* text_rel      = (const float*)d_in[6];
    const float* text_W        = (const float*)d_in[7];
    const float* text_b        = (const float*)d_in[8];
    const float* text_g        = (const float*)d_in[9];
    const float* text_beta     = (const float*)d_in[10];
    const float* fuse_W1       = (const float*)d_in[11];
    const float* fuse_b1       = (const float*)d_in[12];
    const float* fuse_W2       = (const float*)d_in[13];
    const float* fuse_b2       = (const float*)d_in[14];
    const int*   h_index       = (const int*)d_in[15];
    const int*   edge_index    = (const int*)d_in[16];
    const int*   edge_type     = (const int*)d_in[17];
    const int*   text_edge_idx = (const int*)d_in[18];

    const int B  = in_sizes[15];
    const int N  = in_sizes[0] / 64;
    const int E  = in_sizes[17];
    const int ET = in_sizes[18] / 2;
    const int L  = in_sizes[3] / 64;
    const int R  = in_sizes[1] / (L * 64);

    const int* src  = edge_index;
    const int* dst  = edge_index + E;
    const int* tsrc = text_edge_idx;
    const int* tdst = text_edge_idx + ET;

    float* x_s   = (float*)d_out;                    // [B,N,64]
    float* x_t   = (float*)d_ws;                     // [N,64]
    float* agg_t = x_t + (size_t)N * 64;             // [N,64]
    float* agg_s = agg_t + (size_t)N * 64;           // [B,N,64]

    const size_t nd  = (size_t)N * 64;
    const int rows_s = B * N;
    const int tot_s  = rows_s * 64;

    const int gb_init_s  = (tot_s + 255) / 256;
    const int gb_scat_s  = (E * 16 + 255) / 256;
    const int gb_scat_t  = (ET * 16 + 255) / 256;
    const int gb_upd     = 2048;

    // ---- struct branch (state in d_out) ----
    k_init_onehot<<<gb_init_s, 256, 0, stream>>>(x_s, h_index, N, tot_s);
    for (int i = 0; i < L; ++i) {
        k_init_onehot<<<gb_init_s, 256, 0, stream>>>(agg_s, h_index, N, tot_s);
        k_scatter<<<gb_scat_s, 256, 0, stream>>>(
            x_s, agg_s, src, dst, edge_type,
            struct_rel + (size_t)i * R * 64, E, N, B);
        k_update<<<gb_upd, 256, 0, stream>>>(
            struct_W + (size_t)i * 128 * 64, struct_b + i * 64,
            struct_g + i * 64, struct_beta + i * 64, x_s, agg_s, rows_s);
    }

    // ---- text branch (batch-invariant: computed once at [N,64]) ----
    hipMemcpyAsync(x_t, rel_text_init, nd * sizeof(float),
                   hipMemcpyDeviceToDevice, stream);
    for (int i = 0; i < L; ++i) {
        hipMemcpyAsync(agg_t, rel_text_init, nd * sizeof(float),
                       hipMemcpyDeviceToDevice, stream);
        k_scatter<<<gb_scat_t, 256, 0, stream>>>(
            x_t, agg_t, tsrc, tdst, nullptr,
            text_rel + (size_t)i * 64, ET, N, 1);
        k_update<<<gb_upd, 256, 0, stream>>>(
            text_W + (size_t)i * 128 * 64, text_b + i * 64,
            text_g + i * 64, text_beta + i * 64, x_t, agg_t, N);
    }

    // ---- fusion (in place on d_out) ----
    k_fuse<<<gb_upd, 256, 0, stream>>>(
        fuse_W1, fuse_b1, fuse_W2, fuse_b2, x_s, x_t, N, rows_s);
}

// Round 2
// 2893.879 us; speedup vs baseline: 2.5293x; 2.5293x over previous
//
#include <hip/hip_runtime.h>

// ---------------------------------------------------------------------------
// SemmaRelModel: two 6-layer NBFNet branches + MLP fusion.
// D = 64 fixed. One wave (64 lanes) owns one node-row for all dense math.
// Round 2: atomic scatter -> on-device CSR (by dst) + gather aggregation.
//   - CSR built once per graph per launch, reused across 6 layers.
//   - packed edge entry: src | (etype << 27).
// Struct-branch state x_s lives in d_out; text branch computed once at [N,64]
// (batch-invariant).
// ---------------------------------------------------------------------------

// x[idx] = (n == h_index[b]) ? 1 : 0   over [B,N,64]
__global__ __launch_bounds__(256) void k_init_onehot(
    float* __restrict__ x, const int* __restrict__ h_index, int N, int total)
{
    int idx = blockIdx.x * 256 + threadIdx.x;
    if (idx >= total) return;
    int row = idx >> 6;          // b*N + n
    int b = row / N;
    int n = row - b * N;
    x[idx] = (n == h_index[b]) ? 1.0f : 0.0f;
}

// ---- CSR build ----
__global__ __launch_bounds__(256) void k_hist(
    const int* __restrict__ dst, int* __restrict__ cnt, int E)
{
    int e = blockIdx.x * 256 + threadIdx.x;
    if (e < E) atomicAdd(&cnt[dst[e]], 1);
}

// single-block hierarchical exclusive scan: off[0]=0, off[i+1]=sum(cnt[0..i])
__global__ __launch_bounds__(1024) void k_scan(
    const int* __restrict__ cnt, int* __restrict__ off, int n)
{
    __shared__ int wpre[16];
    __shared__ int total_s;
    __shared__ int carry_s;
    int tid = threadIdx.x, lane = tid & 63, w = tid >> 6;
    if (tid == 0) { carry_s = 0; off[0] = 0; }
    __syncthreads();
    for (int base = 0; base < n; base += 1024) {
        int i = base + tid;
        int v = (i < n) ? cnt[i] : 0;
        int s = v;                       // inclusive wave scan
        #pragma unroll
        for (int d = 1; d < 64; d <<= 1) {
            int t = __shfl_up(s, d);
            if (lane >= d) s += t;
        }
        __shared__ int wsum[16];
        if (lane == 63) wsum[w] = s;
        __syncthreads();
        if (w == 0 && lane < 16) {
            int ws = wsum[lane];
            int p = ws;
            #pragma unroll
            for (int d = 1; d < 16; d <<= 1) {
                int t = __shfl_up(p, d);
                if (lane >= d) p += t;
            }
            wpre[lane] = p - ws;         // exclusive prefix of wave sums
            if (lane == 15) total_s = p;
        }
        __syncthreads();
        int carry = carry_s;
        if (i < n) off[i + 1] = carry + wpre[w] + s;
        __syncthreads();
        if (tid == 0) carry_s = carry + total_s;
        __syncthreads();
    }
}

// fill packed CSR entries; cnt is consumed back to 0 by atomicSub
__global__ __launch_bounds__(256) void k_fill(
    const int* __restrict__ src, const int* __restrict__ dst,
    const int* __restrict__ etype,       // may be null -> type 0
    const int* __restrict__ off, int* __restrict__ cnt,
    int* __restrict__ packed, int E)
{
    int e = blockIdx.x * 256 + threadIdx.x;
    if (e >= E) return;
    int d = dst[e];
    int pos = off[d] + atomicSub(&cnt[d], 1) - 1;
    int ty = etype ? etype[e] : 0;
    packed[pos] = src[e] | (ty << 27);
}

// ---- aggregation: agg[b,n,:] = boundary(b,n) + sum_{e: dst=n} x[b,src,:]*rel[ty,:]
// one wave per (b,n); lane = dim.
__global__ __launch_bounds__(256) void k_gather_struct(
    const float* __restrict__ x, float* __restrict__ agg,
    const int* __restrict__ off, const int* __restrict__ packed,
    const float* __restrict__ rel,       // [4,64]
    const int* __restrict__ h_index,
    int N, int BN)
{
    int wid = (blockIdx.x * 256 + threadIdx.x) >> 6;
    int lane = threadIdx.x & 63;
    if (wid >= BN) return;
    int b = wid / N;
    int n = wid - b * N;
    float r0 = rel[0 * 64 + lane], r1 = rel[1 * 64 + lane];
    float r2 = rel[2 * 64 + lane], r3 = rel[3 * 64 + lane];
    const float* xb = x + (size_t)b * N * 64;
    float acc = (n == h_index[b]) ? 1.0f : 0.0f;
    int p0 = off[n], p1 = off[n + 1];
    for (int p = p0; p < p1; ++p) {
        int pk = packed[p];
        int s = pk & 0x03FFFFFF;
        int ty = pk >> 27;
        float r = (ty < 2) ? (ty == 0 ? r0 : r1) : (ty == 2 ? r2 : r3);
        acc += xb[(size_t)s * 64 + lane] * r;
    }
    agg[(size_t)wid * 64 + lane] = acc;
}

__global__ __launch_bounds__(256) void k_gather_text(
    const float* __restrict__ x, float* __restrict__ agg,
    const int* __restrict__ off, const int* __restrict__ packed,
    const float* __restrict__ rel,       // [64]
    const float* __restrict__ init,      // [N,64] boundary
    int N)
{
    int wid = (blockIdx.x * 256 + threadIdx.x) >> 6;
    int lane = threadIdx.x & 63;
    if (wid >= N) return;
    float r = rel[lane];
    float acc = init[(size_t)wid * 64 + lane];
    int p0 = off[wid], p1 = off[wid + 1];
    for (int p = p0; p < p1; ++p) {
        int s = packed[p];
        acc += x[(size_t)s * 64 + lane] * r;
    }
    agg[(size_t)wid * 64 + lane] = acc;
}

// x_row = relu(LN(concat(x_row, agg_row) @ W + b)) + x_row   (in place)
__global__ __launch_bounds__(256) void k_update(
    const float* __restrict__ W,      // [128,64] layer slice
    const float* __restrict__ bias, const float* __restrict__ g,
    const float* __restrict__ beta,
    float* __restrict__ x, const float* __restrict__ agg, int rows)
{
    __shared__ float Wl[128 * 64];
    __shared__ float bl[64], gl[64], betal[64];
    int tid = threadIdx.x;
    for (int i = tid; i < 128 * 64; i += 256) Wl[i] = W[i];
    if (tid < 64) { bl[tid] = bias[tid]; gl[tid] = g[tid]; betal[tid] = beta[tid]; }
    __syncthreads();

    int wave = tid >> 6;
    int lane = tid & 63;
    int wstride = gridDim.x * 4;
    for (int row = blockIdx.x * 4 + wave; row < rows; row += wstride) {
        float xv = x[(size_t)row * 64 + lane];
        float av = agg[(size_t)row * 64 + lane];
        float h = bl[lane];
        #pragma unroll
        for (int k = 0; k < 64; ++k)
            h += __shfl(xv, k) * Wl[k * 64 + lane];
        #pragma unroll
        for (int k = 0; k < 64; ++k)
            h += __shfl(av, k) * Wl[(64 + k) * 64 + lane];
        float s = h;
        #pragma unroll
        for (int off = 32; off >= 1; off >>= 1) s += __shfl_xor(s, off);
        float m = s * (1.0f / 64.0f);
        float c = h - m;
        float v = c * c;
        #pragma unroll
        for (int off = 32; off >= 1; off >>= 1) v += __shfl_xor(v, off);
        v *= (1.0f / 64.0f);
        float y = c * rsqrtf(v + 1e-5f) * gl[lane] + betal[lane];
        y = fmaxf(y, 0.0f) + xv;
        x[(size_t)row * 64 + lane] = y;
    }
}

// out_row = relu(concat(h_row, z_row) @ W1 + b1) @ W2 + b2  (in place on out=h)
__global__ __launch_bounds__(256) void k_fuse(
    const float* __restrict__ W1, const float* __restrict__ b1,
    const float* __restrict__ W2, const float* __restrict__ b2,
    float* __restrict__ out, const float* __restrict__ z, int N, int rows)
{
    __shared__ float W1l[128 * 64];
    __shared__ float W2l[64 * 64];
    __shared__ float b1l[64], b2l[64];
    int tid = threadIdx.x;
    for (int i = tid; i < 128 * 64; i += 256) W1l[i] = W1[i];
    for (int i = tid; i < 64 * 64; i += 256) W2l[i] = W2[i];
    if (tid < 64) { b1l[tid] = b1[tid]; b2l[tid] = b2[tid]; }
    __syncthreads();

    int wave = tid >> 6;
    int lane = tid & 63;
    int wstride = gridDim.x * 4;
    for (int row = blockIdx.x * 4 + wave; row < rows; row += wstride) {
        int n = row % N;
        float hv = out[(size_t)row * 64 + lane];
        float zv = z[(size_t)n * 64 + lane];
        float f = b1l[lane];
        #pragma unroll
        for (int k = 0; k < 64; ++k)
            f += __shfl(hv, k) * W1l[k * 64 + lane];
        #pragma unroll
        for (int k = 0; k < 64; ++k)
            f += __shfl(zv, k) * W1l[(64 + k) * 64 + lane];
        f = fmaxf(f, 0.0f);
        float o = b2l[lane];
        #pragma unroll
        for (int k = 0; k < 64; ++k)
            o += __shfl(f, k) * W2l[k * 64 + lane];
        out[(size_t)row * 64 + lane] = o;
    }
}

extern "C" void kernel_launch(void* const* d_in, const int* in_sizes, int n_in,
                              void* d_out, int out_size, void* d_ws, size_t ws_size,
                              hipStream_t stream)
{
    const float* rel_text_init = (const float*)d_in[0];
    const float* struct_rel    = (const float*)d_in[1];
    const float* struct_W      = (const float*)d_in[2];
    const float* struct_b      = (const float*)d_in[3];
    const float* struct_g      = (const float*)d_in[4];
    const float* struct_beta   = (const float*)d_in[5];
    const float* text_rel      = (const float*)d_in[6];
    const float* text_W        = (const float*)d_in[7];
    const float* text_b        = (const float*)d_in[8];
    const float* text_g        = (const float*)d_in[9];
    const float* text_beta     = (const float*)d_in[10];
    const float* fuse_W1       = (const float*)d_in[11];
    const float* fuse_b1       = (const float*)d_in[12];
    const float* fuse_W2       = (const float*)d_in[13];
    const float* fuse_b2       = (const float*)d_in[14];
    const int*   h_index       = (const int*)d_in[15];
    const int*   edge_index    = (const int*)d_in[16];
    const int*   edge_type     = (const int*)d_in[17];
    const int*   text_edge_idx = (const int*)d_in[18];

    const int B  = in_sizes[15];
    const int N  = in_sizes[0] / 64;
    const int E  = in_sizes[17];
    const int ET = in_sizes[18] / 2;
    const int L  = in_sizes[3] / 64;
    const int R  = in_sizes[1] / (L * 64);

    const int* src  = edge_index;
    const int* dst  = edge_index + E;
    const int* tsrc = text_edge_idx;
    const int* tdst = text_edge_idx + ET;

    // ---- workspace layout ----
    float* x_t   = (float*)d_ws;                     // [N,64]
    float* agg_t = x_t + (size_t)N * 64;             // [N,64]
    float* agg_s = agg_t + (size_t)N * 64;           // [B,N,64]
    int*   cnt_s = (int*)(agg_s + (size_t)B * N * 64);  // [N]
    int*   off_s = cnt_s + N;                        // [N+1]
    int*   pk_s  = off_s + N + 1;                    // [E]
    int*   cnt_t = pk_s + E;                         // [N]
    int*   off_t = cnt_t + N;                        // [N+1]
    int*   pk_t  = off_t + N + 1;                    // [ET]

    float* x_s = (float*)d_out;                      // [B,N,64]

    const size_t nd  = (size_t)N * 64;
    const int rows_s = B * N;
    const int tot_s  = rows_s * 64;

    const int gb_init   = (tot_s + 255) / 256;
    const int gb_e      = (E + 255) / 256;
    const int gb_et     = (ET + 255) / 256;
    const int gb_gath_s = (rows_s * 64 + 255) / 256;   // one wave per (b,n)
    const int gb_gath_t = ((int)nd + 255) / 256;       // one wave per n
    const int gb_upd    = 2048;

    // ---- CSR builds (once per launch, reused across layers) ----
    hipMemsetAsync(cnt_s, 0, (size_t)N * 4, stream);
    hipMemsetAsync(cnt_t, 0, (size_t)N * 4, stream);
    k_hist<<<gb_e, 256, 0, stream>>>(dst, cnt_s, E);
    k_hist<<<gb_et, 256, 0, stream>>>(tdst, cnt_t, ET);
    k_scan<<<1, 1024, 0, stream>>>(cnt_s, off_s, N);
    k_scan<<<1, 1024, 0, stream>>>(cnt_t, off_t, N);
    k_fill<<<gb_e, 256, 0, stream>>>(src, dst, edge_type, off_s, cnt_s, pk_s, E);
    k_fill<<<gb_et, 256, 0, stream>>>(tsrc, tdst, nullptr, off_t, cnt_t, pk_t, ET);

    // ---- struct branch (state in d_out) ----
    k_init_onehot<<<gb_init, 256, 0, stream>>>(x_s, h_index, N, tot_s);
    for (int i = 0; i < L; ++i) {
        k_gather_struct<<<gb_gath_s, 256, 0, stream>>>(
            x_s, agg_s, off_s, pk_s,
            struct_rel + (size_t)i * R * 64, h_index, N, rows_s);
        k_update<<<gb_upd, 256, 0, stream>>>(
            struct_W + (size_t)i * 128 * 64, struct_b + i * 64,
            struct_g + i * 64, struct_beta + i * 64, x_s, agg_s, rows_s);
    }

    // ---- text branch (batch-invariant: computed once at [N,64]) ----
    hipMemcpyAsync(x_t, rel_text_init, nd * sizeof(float),
                   hipMemcpyDeviceToDevice, stream);
    for (int i = 0; i < L; ++i) {
        k_gather_text<<<gb_gath_t, 256, 0, stream>>>(
            x_t, agg_t, off_t, pk_t,
            text_rel + (size_t)i * 64, rel_text_init, N);
        k_update<<<gb_upd, 256, 0, stream>>>(
            text_W + (size_t)i * 128 * 64, text_b + i * 64,
            text_g + i * 64, text_beta + i * 64, x_t, agg_t, N);
    }

    // ---- fusion (in place on d_out) ----
    k_fuse<<<gb_upd, 256, 0, stream>>>(
        fuse_W1, fuse_b1, fuse_W2, fuse_b2, x_s, x_t, N, rows_s);
}

// Round 3
// 2483.098 us; speedup vs baseline: 2.9478x; 1.1654x over previous
//
#include <hip/hip_runtime.h>

// ---------------------------------------------------------------------------
// SemmaRelModel: two 6-layer NBFNet branches + MLP fusion.
// Round 3: dense layers -> thread-per-row register GEMV (no shuffles).
//   - acc[64] in VGPRs, W in LDS read at wave-uniform addresses (broadcast).
//   - LayerNorm entirely in per-thread registers.
// Aggregation: CSR-by-dst gather (built on device once per launch).
// Struct state x_s lives in d_out; text branch computed once at [N,64].
// ---------------------------------------------------------------------------

// x[idx] = (n == h_index[b]) ? 1 : 0   over [B,N,64]
__global__ __launch_bounds__(256) void k_init_onehot(
    float* __restrict__ x, const int* __restrict__ h_index, int N, int total)
{
    int idx = blockIdx.x * 256 + threadIdx.x;
    if (idx >= total) return;
    int row = idx >> 6;
    int b = row / N;
    int n = row - b * N;
    x[idx] = (n == h_index[b]) ? 1.0f : 0.0f;
}

// ---- CSR build ----
__global__ __launch_bounds__(256) void k_hist(
    const int* __restrict__ dst, int* __restrict__ cnt, int E)
{
    int e = blockIdx.x * 256 + threadIdx.x;
    if (e < E) atomicAdd(&cnt[dst[e]], 1);
}

__global__ __launch_bounds__(1024) void k_scan(
    const int* __restrict__ cnt, int* __restrict__ off, int n)
{
    __shared__ int wpre[16];
    __shared__ int total_s;
    __shared__ int carry_s;
    int tid = threadIdx.x, lane = tid & 63, w = tid >> 6;
    if (tid == 0) { carry_s = 0; off[0] = 0; }
    __syncthreads();
    for (int base = 0; base < n; base += 1024) {
        int i = base + tid;
        int v = (i < n) ? cnt[i] : 0;
        int s = v;
        #pragma unroll
        for (int d = 1; d < 64; d <<= 1) {
            int t = __shfl_up(s, d);
            if (lane >= d) s += t;
        }
        __shared__ int wsum[16];
        if (lane == 63) wsum[w] = s;
        __syncthreads();
        if (w == 0 && lane < 16) {
            int ws = wsum[lane];
            int p = ws;
            #pragma unroll
            for (int d = 1; d < 16; d <<= 1) {
                int t = __shfl_up(p, d);
                if (lane >= d) p += t;
            }
            wpre[lane] = p - ws;
            if (lane == 15) total_s = p;
        }
        __syncthreads();
        int carry = carry_s;
        if (i < n) off[i + 1] = carry + wpre[w] + s;
        __syncthreads();
        if (tid == 0) carry_s = carry + total_s;
        __syncthreads();
    }
}

__global__ __launch_bounds__(256) void k_fill(
    const int* __restrict__ src, const int* __restrict__ dst,
    const int* __restrict__ etype,
    const int* __restrict__ off, int* __restrict__ cnt,
    int* __restrict__ packed, int E)
{
    int e = blockIdx.x * 256 + threadIdx.x;
    if (e >= E) return;
    int d = dst[e];
    int pos = off[d] + atomicSub(&cnt[d], 1) - 1;
    int ty = etype ? etype[e] : 0;
    packed[pos] = src[e] | (ty << 27);
}

// ---- aggregation: one wave per (b,n); lane = dim ----
__global__ __launch_bounds__(256) void k_gather_struct(
    const float* __restrict__ x, float* __restrict__ agg,
    const int* __restrict__ off, const int* __restrict__ packed,
    const float* __restrict__ rel,       // [4,64]
    const int* __restrict__ h_index,
    int N, int BN)
{
    int wid = (blockIdx.x * 256 + threadIdx.x) >> 6;
    int lane = threadIdx.x & 63;
    if (wid >= BN) return;
    int b = wid / N;
    int n = wid - b * N;
    float r0 = rel[0 * 64 + lane], r1 = rel[1 * 64 + lane];
    float r2 = rel[2 * 64 + lane], r3 = rel[3 * 64 + lane];
    const float* xb = x + (size_t)b * N * 64;
    float acc = (n == h_index[b]) ? 1.0f : 0.0f;
    int p0 = off[n], p1 = off[n + 1];
    for (int p = p0; p < p1; ++p) {
        int pk = packed[p];
        int s = pk & 0x03FFFFFF;
        int ty = pk >> 27;
        float r = (ty < 2) ? (ty == 0 ? r0 : r1) : (ty == 2 ? r2 : r3);
        acc += xb[(size_t)s * 64 + lane] * r;
    }
    agg[(size_t)wid * 64 + lane] = acc;
}

__global__ __launch_bounds__(256) void k_gather_text(
    const float* __restrict__ x, float* __restrict__ agg,
    const int* __restrict__ off, const int* __restrict__ packed,
    const float* __restrict__ rel,       // [64]
    const float* __restrict__ init,      // [N,64]
    int N)
{
    int wid = (blockIdx.x * 256 + threadIdx.x) >> 6;
    int lane = threadIdx.x & 63;
    if (wid >= N) return;
    float r = rel[lane];
    float acc = init[(size_t)wid * 64 + lane];
    int p0 = off[wid], p1 = off[wid + 1];
    for (int p = p0; p < p1; ++p) {
        int s = packed[p];
        acc += x[(size_t)s * 64 + lane] * r;
    }
    agg[(size_t)wid * 64 + lane] = acc;
}

// ---- dense update: one THREAD per row, acc[64] in VGPRs ----
// x_row = relu(LN(concat(x_row, agg_row) @ W + b)) + x_row   (in place)
__global__ __launch_bounds__(256) void k_update(
    const float* __restrict__ W,      // [128,64]
    const float* __restrict__ bias, const float* __restrict__ g,
    const float* __restrict__ beta,
    float* __restrict__ x, const float* __restrict__ agg, int rows)
{
    __shared__ float Wl[128 * 64];
    __shared__ float bl[64], gl[64], bel[64];
    int tid = threadIdx.x;
    {
        const float4* W4 = (const float4*)W;
        float4* Wl4 = (float4*)Wl;
        #pragma unroll
        for (int i = 0; i < 8; ++i) Wl4[tid + i * 256] = W4[tid + i * 256];
        if (tid < 64) { bl[tid] = bias[tid]; gl[tid] = g[tid]; bel[tid] = beta[tid]; }
    }
    __syncthreads();

    int row = blockIdx.x * 256 + tid;
    if (row >= rows) return;
    const float* xr = x + (size_t)row * 64;
    const float* ar = agg + (size_t)row * 64;

    float acc[64];
    #pragma unroll
    for (int j = 0; j < 64; ++j) acc[j] = bl[j];

    #pragma unroll
    for (int kc = 0; kc < 128; kc += 16) {
        float in[16];
        const float* sp = (kc < 64) ? (xr + kc) : (ar + (kc - 64));
        *(float4*)(in + 0)  = *(const float4*)(sp + 0);
        *(float4*)(in + 4)  = *(const float4*)(sp + 4);
        *(float4*)(in + 8)  = *(const float4*)(sp + 8);
        *(float4*)(in + 12) = *(const float4*)(sp + 12);
        #pragma unroll
        for (int kk = 0; kk < 16; ++kk) {
            float v = in[kk];
            const float* wrow = &Wl[(kc + kk) * 64];
            #pragma unroll
            for (int j = 0; j < 64; j += 4) {
                float4 w = *(const float4*)(wrow + j);   // wave-uniform: broadcast
                acc[j + 0] = fmaf(v, w.x, acc[j + 0]);
                acc[j + 1] = fmaf(v, w.y, acc[j + 1]);
                acc[j + 2] = fmaf(v, w.z, acc[j + 2]);
                acc[j + 3] = fmaf(v, w.w, acc[j + 3]);
            }
        }
    }

    // LayerNorm + relu + residual, all in registers
    float s = 0.f;
    #pragma unroll
    for (int j = 0; j < 64; ++j) s += acc[j];
    float m = s * (1.0f / 64.0f);
    float vs = 0.f;
    #pragma unroll
    for (int j = 0; j < 64; ++j) { float c = acc[j] - m; vs += c * c; }
    float inv = rsqrtf(vs * (1.0f / 64.0f) + 1e-5f);
    float* xw = x + (size_t)row * 64;
    #pragma unroll
    for (int j = 0; j < 64; j += 4) {
        float4 xv = *(const float4*)(xr + j);
        float4 y;
        y.x = fmaxf((acc[j + 0] - m) * inv * gl[j + 0] + bel[j + 0], 0.f) + xv.x;
        y.y = fmaxf((acc[j + 1] - m) * inv * gl[j + 1] + bel[j + 1], 0.f) + xv.y;
        y.z = fmaxf((acc[j + 2] - m) * inv * gl[j + 2] + bel[j + 2], 0.f) + xv.z;
        y.w = fmaxf((acc[j + 3] - m) * inv * gl[j + 3] + bel[j + 3], 0.f) + xv.w;
        *(float4*)(xw + j) = y;
    }
}

// ---- fusion: one THREAD per row ----
// out_row = relu(concat(h_row, z_row) @ W1 + b1) @ W2 + b2  (in place on out=h)
__global__ __launch_bounds__(256) void k_fuse(
    const float* __restrict__ W1, const float* __restrict__ b1,
    const float* __restrict__ W2, const float* __restrict__ b2,
    float* __restrict__ out, const float* __restrict__ z, int N, int rows)
{
    __shared__ float W1l[128 * 64];
    __shared__ float W2l[64 * 64];
    __shared__ float b1l[64], b2l[64];
    int tid = threadIdx.x;
    {
        const float4* Wa = (const float4*)W1;
        float4* Wla = (float4*)W1l;
        #pragma unroll
        for (int i = 0; i < 8; ++i) Wla[tid + i * 256] = Wa[tid + i * 256];
        const float4* Wb = (const float4*)W2;
        float4* Wlb = (float4*)W2l;
        #pragma unroll
        for (int i = 0; i < 4; ++i) Wlb[tid + i * 256] = Wb[tid + i * 256];
        if (tid < 64) { b1l[tid] = b1[tid]; b2l[tid] = b2[tid]; }
    }
    __syncthreads();

    int row = blockIdx.x * 256 + tid;
    if (row >= rows) return;
    int n = row % N;
    const float* hr = out + (size_t)row * 64;
    const float* zr = z + (size_t)n * 64;

    float f[64];
    #pragma unroll
    for (int j = 0; j < 64; ++j) f[j] = b1l[j];

    #pragma unroll
    for (int kc = 0; kc < 128; kc += 16) {
        float in[16];
        const float* sp = (kc < 64) ? (hr + kc) : (zr + (kc - 64));
        *(float4*)(in + 0)  = *(const float4*)(sp + 0);
        *(float4*)(in + 4)  = *(const float4*)(sp + 4);
        *(float4*)(in + 8)  = *(const float4*)(sp + 8);
        *(float4*)(in + 12) = *(const float4*)(sp + 12);
        #pragma unroll
        for (int kk = 0; kk < 16; ++kk) {
            float v = in[kk];
            const float* wrow = &W1l[(kc + kk) * 64];
            #pragma unroll
            for (int j = 0; j < 64; j += 4) {
                float4 w = *(const float4*)(wrow + j);
                f[j + 0] = fmaf(v, w.x, f[j + 0]);
                f[j + 1] = fmaf(v, w.y, f[j + 1]);
                f[j + 2] = fmaf(v, w.z, f[j + 2]);
                f[j + 3] = fmaf(v, w.w, f[j + 3]);
            }
        }
    }
    #pragma unroll
    for (int j = 0; j < 64; ++j) f[j] = fmaxf(f[j], 0.f);

    float o[64];
    #pragma unroll
    for (int j = 0; j < 64; ++j) o[j] = b2l[j];
    #pragma unroll
    for (int k = 0; k < 64; ++k) {
        float v = f[k];
        const float* wrow = &W2l[k * 64];
        #pragma unroll
        for (int j = 0; j < 64; j += 4) {
            float4 w = *(const float4*)(wrow + j);
            o[j + 0] = fmaf(v, w.x, o[j + 0]);
            o[j + 1] = fmaf(v, w.y, o[j + 1]);
            o[j + 2] = fmaf(v, w.z, o[j + 2]);
            o[j + 3] = fmaf(v, w.w, o[j + 3]);
        }
    }
    float* ow = out + (size_t)row * 64;
    #pragma unroll
    for (int j = 0; j < 64; j += 4) {
        float4 y; y.x = o[j]; y.y = o[j + 1]; y.z = o[j + 2]; y.w = o[j + 3];
        *(float4*)(ow + j) = y;
    }
}

extern "C" void kernel_launch(void* const* d_in, const int* in_sizes, int n_in,
                              void* d_out, int out_size, void* d_ws, size_t ws_size,
                              hipStream_t stream)
{
    const float* rel_text_init = (const float*)d_in[0];
    const float* struct_rel    = (const float*)d_in[1];
    const float* struct_W      = (const float*)d_in[2];
    const float* struct_b      = (const float*)d_in[3];
    const float* struct_g      = (const float*)d_in[4];
    const float* struct_beta   = (const float*)d_in[5];
    const float* text_rel      = (const float*)d_in[6];
    const float* text_W        = (const float*)d_in[7];
    const float* text_b        = (const float*)d_in[8];
    const float* text_g        = (const float*)d_in[9];
    const float* text_beta     = (const float*)d_in[10];
    const float* fuse_W1       = (const float*)d_in[11];
    const float* fuse_b1       = (const float*)d_in[12];
    const float* fuse_W2       = (const float*)d_in[13];
    const float* fuse_b2       = (const float*)d_in[14];
    const int*   h_index       = (const int*)d_in[15];
    const int*   edge_index    = (const int*)d_in[16];
    const int*   edge_type     = (const int*)d_in[17];
    const int*   text_edge_idx = (const int*)d_in[18];

    const int B  = in_sizes[15];
    const int N  = in_sizes[0] / 64;
    const int E  = in_sizes[17];
    const int ET = in_sizes[18] / 2;
    const int L  = in_sizes[3] / 64;
    const int R  = in_sizes[1] / (L * 64);

    const int* src  = edge_index;
    const int* dst  = edge_index + E;
    const int* tsrc = text_edge_idx;
    const int* tdst = text_edge_idx + ET;

    // ---- workspace layout ----
    float* x_t   = (float*)d_ws;                     // [N,64]
    float* agg_t = x_t + (size_t)N * 64;             // [N,64]
    float* agg_s = agg_t + (size_t)N * 64;           // [B,N,64]
    int*   cnt_s = (int*)(agg_s + (size_t)B * N * 64);  // [N]
    int*   off_s = cnt_s + N;                        // [N+1]
    int*   pk_s  = off_s + N + 1;                    // [E]
    int*   cnt_t = pk_s + E;                         // [N]
    int*   off_t = cnt_t + N;                        // [N+1]
    int*   pk_t  = off_t + N + 1;                    // [ET]

    float* x_s = (float*)d_out;                      // [B,N,64]

    const size_t nd  = (size_t)N * 64;
    const int rows_s = B * N;
    const int tot_s  = rows_s * 64;

    const int gb_init   = (tot_s + 255) / 256;
    const int gb_e      = (E + 255) / 256;
    const int gb_et     = (ET + 255) / 256;
    const int gb_gath_s = (rows_s * 64 + 255) / 256;
    const int gb_gath_t = ((int)nd + 255) / 256;
    const int gb_upd_s  = (rows_s + 255) / 256;
    const int gb_upd_t  = (N + 255) / 256;

    // ---- CSR builds ----
    hipMemsetAsync(cnt_s, 0, (size_t)N * 4, stream);
    hipMemsetAsync(cnt_t, 0, (size_t)N * 4, stream);
    k_hist<<<gb_e, 256, 0, stream>>>(dst, cnt_s, E);
    k_hist<<<gb_et, 256, 0, stream>>>(tdst, cnt_t, ET);
    k_scan<<<1, 1024, 0, stream>>>(cnt_s, off_s, N);
    k_scan<<<1, 1024, 0, stream>>>(cnt_t, off_t, N);
    k_fill<<<gb_e, 256, 0, stream>>>(src, dst, edge_type, off_s, cnt_s, pk_s, E);
    k_fill<<<gb_et, 256, 0, stream>>>(tsrc, tdst, nullptr, off_t, cnt_t, pk_t, ET);

    // ---- struct branch (state in d_out) ----
    k_init_onehot<<<gb_init, 256, 0, stream>>>(x_s, h_index, N, tot_s);
    for (int i = 0; i < L; ++i) {
        k_gather_struct<<<gb_gath_s, 256, 0, stream>>>(
            x_s, agg_s, off_s, pk_s,
            struct_rel + (size_t)i * R * 64, h_index, N, rows_s);
        k_update<<<gb_upd_s, 256, 0, stream>>>(
            struct_W + (size_t)i * 128 * 64, struct_b + i * 64,
            struct_g + i * 64, struct_beta + i * 64, x_s, agg_s, rows_s);
    }

    // ---- text branch (batch-invariant) ----
    hipMemcpyAsync(x_t, rel_text_init, nd * sizeof(float),
                   hipMemcpyDeviceToDevice, stream);
    for (int i = 0; i < L; ++i) {
        k_gather_text<<<gb_gath_t, 256, 0, stream>>>(
            x_t, agg_t, off_t, pk_t,
            text_rel + (size_t)i * 64, rel_text_init, N);
        k_update<<<gb_upd_t, 256, 0, stream>>>(
            text_W + (size_t)i * 128 * 64, text_b + i * 64,
            text_g + i * 64, text_beta + i * 64, x_t, agg_t, N);
    }

    // ---- fusion ----
    k_fuse<<<gb_upd_s, 256, 0, stream>>>(
        fuse_W1, fuse_b1, fuse_W2, fuse_b2, x_s, x_t, N, rows_s);
}

// Round 4
// 1726.936 us; speedup vs baseline: 4.2385x; 1.4379x over previous
//
#include <hip/hip_runtime.h>

// ---------------------------------------------------------------------------
// SemmaRelModel: two 6-layer NBFNet branches + MLP fusion.
// Round 4: fix k_fuse VGPR spill (256 VGPR, 2.5 GB scratch traffic/dispatch).
//   Second GEMV now chunked: f[64] whole + o[16] per chunk -> peak ~90 live
//   floats, no spill. Everything else unchanged from round 3.
// ---------------------------------------------------------------------------

// x[idx] = (n == h_index[b]) ? 1 : 0   over [B,N,64]
__global__ __launch_bounds__(256) void k_init_onehot(
    float* __restrict__ x, const int* __restrict__ h_index, int N, int total)
{
    int idx = blockIdx.x * 256 + threadIdx.x;
    if (idx >= total) return;
    int row = idx >> 6;
    int b = row / N;
    int n = row - b * N;
    x[idx] = (n == h_index[b]) ? 1.0f : 0.0f;
}

// ---- CSR build ----
__global__ __launch_bounds__(256) void k_hist(
    const int* __restrict__ dst, int* __restrict__ cnt, int E)
{
    int e = blockIdx.x * 256 + threadIdx.x;
    if (e < E) atomicAdd(&cnt[dst[e]], 1);
}

__global__ __launch_bounds__(1024) void k_scan(
    const int* __restrict__ cnt, int* __restrict__ off, int n)
{
    __shared__ int wpre[16];
    __shared__ int total_s;
    __shared__ int carry_s;
    int tid = threadIdx.x, lane = tid & 63, w = tid >> 6;
    if (tid == 0) { carry_s = 0; off[0] = 0; }
    __syncthreads();
    for (int base = 0; base < n; base += 1024) {
        int i = base + tid;
        int v = (i < n) ? cnt[i] : 0;
        int s = v;
        #pragma unroll
        for (int d = 1; d < 64; d <<= 1) {
            int t = __shfl_up(s, d);
            if (lane >= d) s += t;
        }
        __shared__ int wsum[16];
        if (lane == 63) wsum[w] = s;
        __syncthreads();
        if (w == 0 && lane < 16) {
            int ws = wsum[lane];
            int p = ws;
            #pragma unroll
            for (int d = 1; d < 16; d <<= 1) {
                int t = __shfl_up(p, d);
                if (lane >= d) p += t;
            }
            wpre[lane] = p - ws;
            if (lane == 15) total_s = p;
        }
        __syncthreads();
        int carry = carry_s;
        if (i < n) off[i + 1] = carry + wpre[w] + s;
        __syncthreads();
        if (tid == 0) carry_s = carry + total_s;
        __syncthreads();
    }
}

__global__ __launch_bounds__(256) void k_fill(
    const int* __restrict__ src, const int* __restrict__ dst,
    const int* __restrict__ etype,
    const int* __restrict__ off, int* __restrict__ cnt,
    int* __restrict__ packed, int E)
{
    int e = blockIdx.x * 256 + threadIdx.x;
    if (e >= E) return;
    int d = dst[e];
    int pos = off[d] + atomicSub(&cnt[d], 1) - 1;
    int ty = etype ? etype[e] : 0;
    packed[pos] = src[e] | (ty << 27);
}

// ---- aggregation: one wave per (b,n); lane = dim ----
__global__ __launch_bounds__(256) void k_gather_struct(
    const float* __restrict__ x, float* __restrict__ agg,
    const int* __restrict__ off, const int* __restrict__ packed,
    const float* __restrict__ rel,       // [4,64]
    const int* __restrict__ h_index,
    int N, int BN)
{
    int wid = (blockIdx.x * 256 + threadIdx.x) >> 6;
    int lane = threadIdx.x & 63;
    if (wid >= BN) return;
    int b = wid / N;
    int n = wid - b * N;
    float r0 = rel[0 * 64 + lane], r1 = rel[1 * 64 + lane];
    float r2 = rel[2 * 64 + lane], r3 = rel[3 * 64 + lane];
    const float* xb = x + (size_t)b * N * 64;
    float acc = (n == h_index[b]) ? 1.0f : 0.0f;
    int p0 = off[n], p1 = off[n + 1];
    for (int p = p0; p < p1; ++p) {
        int pk = packed[p];
        int s = pk & 0x03FFFFFF;
        int ty = pk >> 27;
        float r = (ty < 2) ? (ty == 0 ? r0 : r1) : (ty == 2 ? r2 : r3);
        acc += xb[(size_t)s * 64 + lane] * r;
    }
    agg[(size_t)wid * 64 + lane] = acc;
}

__global__ __launch_bounds__(256) void k_gather_text(
    const float* __restrict__ x, float* __restrict__ agg,
    const int* __restrict__ off, const int* __restrict__ packed,
    const float* __restrict__ rel,       // [64]
    const float* __restrict__ init,      // [N,64]
    int N)
{
    int wid = (blockIdx.x * 256 + threadIdx.x) >> 6;
    int lane = threadIdx.x & 63;
    if (wid >= N) return;
    float r = rel[lane];
    float acc = init[(size_t)wid * 64 + lane];
    int p0 = off[wid], p1 = off[wid + 1];
    for (int p = p0; p < p1; ++p) {
        int s = packed[p];
        acc += x[(size_t)s * 64 + lane] * r;
    }
    agg[(size_t)wid * 64 + lane] = acc;
}

// ---- dense update: one THREAD per row, acc[64] in VGPRs ----
// x_row = relu(LN(concat(x_row, agg_row) @ W + b)) + x_row   (in place)
__global__ __launch_bounds__(256) void k_update(
    const float* __restrict__ W,      // [128,64]
    const float* __restrict__ bias, const float* __restrict__ g,
    const float* __restrict__ beta,
    float* __restrict__ x, const float* __restrict__ agg, int rows)
{
    __shared__ float Wl[128 * 64];
    __shared__ float bl[64], gl[64], bel[64];
    int tid = threadIdx.x;
    {
        const float4* W4 = (const float4*)W;
        float4* Wl4 = (float4*)Wl;
        #pragma unroll
        for (int i = 0; i < 8; ++i) Wl4[tid + i * 256] = W4[tid + i * 256];
        if (tid < 64) { bl[tid] = bias[tid]; gl[tid] = g[tid]; bel[tid] = beta[tid]; }
    }
    __syncthreads();

    int row = blockIdx.x * 256 + tid;
    if (row >= rows) return;
    const float* xr = x + (size_t)row * 64;
    const float* ar = agg + (size_t)row * 64;

    float acc[64];
    #pragma unroll
    for (int j = 0; j < 64; ++j) acc[j] = bl[j];

    #pragma unroll
    for (int kc = 0; kc < 128; kc += 16) {
        float in[16];
        const float* sp = (kc < 64) ? (xr + kc) : (ar + (kc - 64));
        *(float4*)(in + 0)  = *(const float4*)(sp + 0);
        *(float4*)(in + 4)  = *(const float4*)(sp + 4);
        *(float4*)(in + 8)  = *(const float4*)(sp + 8);
        *(float4*)(in + 12) = *(const float4*)(sp + 12);
        #pragma unroll
        for (int kk = 0; kk < 16; ++kk) {
            float v = in[kk];
            const float* wrow = &Wl[(kc + kk) * 64];
            #pragma unroll
            for (int j = 0; j < 64; j += 4) {
                float4 w = *(const float4*)(wrow + j);   // wave-uniform: broadcast
                acc[j + 0] = fmaf(v, w.x, acc[j + 0]);
                acc[j + 1] = fmaf(v, w.y, acc[j + 1]);
                acc[j + 2] = fmaf(v, w.z, acc[j + 2]);
                acc[j + 3] = fmaf(v, w.w, acc[j + 3]);
            }
        }
    }

    // LayerNorm + relu + residual, all in registers
    float s = 0.f;
    #pragma unroll
    for (int j = 0; j < 64; ++j) s += acc[j];
    float m = s * (1.0f / 64.0f);
    float vs = 0.f;
    #pragma unroll
    for (int j = 0; j < 64; ++j) { float c = acc[j] - m; vs += c * c; }
    float inv = rsqrtf(vs * (1.0f / 64.0f) + 1e-5f);
    float* xw = x + (size_t)row * 64;
    #pragma unroll
    for (int j = 0; j < 64; j += 4) {
        float4 xv = *(const float4*)(xr + j);
        float4 y;
        y.x = fmaxf((acc[j + 0] - m) * inv * gl[j + 0] + bel[j + 0], 0.f) + xv.x;
        y.y = fmaxf((acc[j + 1] - m) * inv * gl[j + 1] + bel[j + 1], 0.f) + xv.y;
        y.z = fmaxf((acc[j + 2] - m) * inv * gl[j + 2] + bel[j + 2], 0.f) + xv.z;
        y.w = fmaxf((acc[j + 3] - m) * inv * gl[j + 3] + bel[j + 3], 0.f) + xv.w;
        *(float4*)(xw + j) = y;
    }
}

// ---- fusion: one THREAD per row; second GEMV chunked to avoid spill ----
// out_row = relu(concat(h_row, z_row) @ W1 + b1) @ W2 + b2  (in place on out=h)
__global__ __launch_bounds__(256) void k_fuse(
    const float* __restrict__ W1, const float* __restrict__ b1,
    const float* __restrict__ W2, const float* __restrict__ b2,
    float* __restrict__ out, const float* __restrict__ z, int N, int rows)
{
    __shared__ float W1l[128 * 64];
    __shared__ float W2l[64 * 64];
    __shared__ float b1l[64], b2l[64];
    int tid = threadIdx.x;
    {
        const float4* Wa = (const float4*)W1;
        float4* Wla = (float4*)W1l;
        #pragma unroll
        for (int i = 0; i < 8; ++i) Wla[tid + i * 256] = Wa[tid + i * 256];
        const float4* Wb = (const float4*)W2;
        float4* Wlb = (float4*)W2l;
        #pragma unroll
        for (int i = 0; i < 4; ++i) Wlb[tid + i * 256] = Wb[tid + i * 256];
        if (tid < 64) { b1l[tid] = b1[tid]; b2l[tid] = b2[tid]; }
    }
    __syncthreads();

    int row = blockIdx.x * 256 + tid;
    if (row >= rows) return;
    int n = row % N;
    const float* hr = out + (size_t)row * 64;
    const float* zr = z + (size_t)n * 64;

    // first GEMV: f[64] = relu(concat(h,z) @ W1 + b1)
    float f[64];
    #pragma unroll
    for (int j = 0; j < 64; ++j) f[j] = b1l[j];

    #pragma unroll
    for (int kc = 0; kc < 128; kc += 16) {
        float in[16];
        const float* sp = (kc < 64) ? (hr + kc) : (zr + (kc - 64));
        *(float4*)(in + 0)  = *(const float4*)(sp + 0);
        *(float4*)(in + 4)  = *(const float4*)(sp + 4);
        *(float4*)(in + 8)  = *(const float4*)(sp + 8);
        *(float4*)(in + 12) = *(const float4*)(sp + 12);
        #pragma unroll
        for (int kk = 0; kk < 16; ++kk) {
            float v = in[kk];
            const float* wrow = &W1l[(kc + kk) * 64];
            #pragma unroll
            for (int j = 0; j < 64; j += 4) {
                float4 w = *(const float4*)(wrow + j);
                f[j + 0] = fmaf(v, w.x, f[j + 0]);
                f[j + 1] = fmaf(v, w.y, f[j + 1]);
                f[j + 2] = fmaf(v, w.z, f[j + 2]);
                f[j + 3] = fmaf(v, w.w, f[j + 3]);
            }
        }
    }
    #pragma unroll
    for (int j = 0; j < 64; ++j) f[j] = fmaxf(f[j], 0.f);

    // second GEMV in chunks of 16 outputs: o[16] live, no spill
    float* ow = out + (size_t)row * 64;
    #pragma unroll
    for (int jc = 0; jc < 64; jc += 16) {
        float o[16];
        #pragma unroll
        for (int j = 0; j < 16; ++j) o[j] = b2l[jc + j];
        #pragma unroll
        for (int k = 0; k < 64; ++k) {
            float v = f[k];
            const float* wrow = &W2l[k * 64 + jc];
            #pragma unroll
            for (int j = 0; j < 16; j += 4) {
                float4 w = *(const float4*)(wrow + j);
                o[j + 0] = fmaf(v, w.x, o[j + 0]);
                o[j + 1] = fmaf(v, w.y, o[j + 1]);
                o[j + 2] = fmaf(v, w.z, o[j + 2]);
                o[j + 3] = fmaf(v, w.w, o[j + 3]);
            }
        }
        #pragma unroll
        for (int j = 0; j < 16; j += 4) {
            float4 y; y.x = o[j]; y.y = o[j + 1]; y.z = o[j + 2]; y.w = o[j + 3];
            *(float4*)(ow + jc + j) = y;
        }
    }
}

extern "C" void kernel_launch(void* const* d_in, const int* in_sizes, int n_in,
                              void* d_out, int out_size, void* d_ws, size_t ws_size,
                              hipStream_t stream)
{
    const float* rel_text_init = (const float*)d_in[0];
    const float* struct_rel    = (const float*)d_in[1];
    const float* struct_W      = (const float*)d_in[2];
    const float* struct_b      = (const float*)d_in[3];
    const float* struct_g      = (const float*)d_in[4];
    const float* struct_beta   = (const float*)d_in[5];
    const float* text_rel      = (const float*)d_in[6];
    const float* text_W        = (const float*)d_in[7];
    const float* text_b        = (const float*)d_in[8];
    const float* text_g        = (const float*)d_in[9];
    const float* text_beta     = (const float*)d_in[10];
    const float* fuse_W1       = (const float*)d_in[11];
    const float* fuse_b1       = (const float*)d_in[12];
    const float* fuse_W2       = (const float*)d_in[13];
    const float* fuse_b2       = (const float*)d_in[14];
    const int*   h_index       = (const int*)d_in[15];
    const int*   edge_index    = (const int*)d_in[16];
    const int*   edge_type     = (const int*)d_in[17];
    const int*   text_edge_idx = (const int*)d_in[18];

    const int B  = in_sizes[15];
    const int N  = in_sizes[0] / 64;
    const int E  = in_sizes[17];
    const int ET = in_sizes[18] / 2;
    const int L  = in_sizes[3] / 64;
    const int R  = in_sizes[1] / (L * 64);

    const int* src  = edge_index;
    const int* dst  = edge_index + E;
    const int* tsrc = text_edge_idx;
    const int* tdst = text_edge_idx + ET;

    // ---- workspace layout ----
    float* x_t   = (float*)d_ws;                     // [N,64]
    float* agg_t = x_t + (size_t)N * 64;             // [N,64]
    float* agg_s = agg_t + (size_t)N * 64;           // [B,N,64]
    int*   cnt_s = (int*)(agg_s + (size_t)B * N * 64);  // [N]
    int*   off_s = cnt_s + N;                        // [N+1]
    int*   pk_s  = off_s + N + 1;                    // [E]
    int*   cnt_t = pk_s + E;                         // [N]
    int*   off_t = cnt_t + N;                        // [N+1]
    int*   pk_t  = off_t + N + 1;                    // [ET]

    float* x_s = (float*)d_out;                      // [B,N,64]

    const size_t nd  = (size_t)N * 64;
    const int rows_s = B * N;
    const int tot_s  = rows_s * 64;

    const int gb_init   = (tot_s + 255) / 256;
    const int gb_e      = (E + 255) / 256;
    const int gb_et     = (ET + 255) / 256;
    const int gb_gath_s = (rows_s * 64 + 255) / 256;
    const int gb_gath_t = ((int)nd + 255) / 256;
    const int gb_upd_s  = (rows_s + 255) / 256;
    const int gb_upd_t  = (N + 255) / 256;

    // ---- CSR builds ----
    hipMemsetAsync(cnt_s, 0, (size_t)N * 4, stream);
    hipMemsetAsync(cnt_t, 0, (size_t)N * 4, stream);
    k_hist<<<gb_e, 256, 0, stream>>>(dst, cnt_s, E);
    k_hist<<<gb_et, 256, 0, stream>>>(tdst, cnt_t, ET);
    k_scan<<<1, 1024, 0, stream>>>(cnt_s, off_s, N);
    k_scan<<<1, 1024, 0, stream>>>(cnt_t, off_t, N);
    k_fill<<<gb_e, 256, 0, stream>>>(src, dst, edge_type, off_s, cnt_s, pk_s, E);
    k_fill<<<gb_et, 256, 0, stream>>>(tsrc, tdst, nullptr, off_t, cnt_t, pk_t, ET);

    // ---- struct branch (state in d_out) ----
    k_init_onehot<<<gb_init, 256, 0, stream>>>(x_s, h_index, N, tot_s);
    for (int i = 0; i < L; ++i) {
        k_gather_struct<<<gb_gath_s, 256, 0, stream>>>(
            x_s, agg_s, off_s, pk_s,
            struct_rel + (size_t)i * R * 64, h_index, N, rows_s);
        k_update<<<gb_upd_s, 256, 0, stream>>>(
            struct_W + (size_t)i * 128 * 64, struct_b + i * 64,
            struct_g + i * 64, struct_beta + i * 64, x_s, agg_s, rows_s);
    }

    // ---- text branch (batch-invariant) ----
    hipMemcpyAsync(x_t, rel_text_init, nd * sizeof(float),
                   hipMemcpyDeviceToDevice, stream);
    for (int i = 0; i < L; ++i) {
        k_gather_text<<<gb_gath_t, 256, 0, stream>>>(
            x_t, agg_t, off_t, pk_t,
            text_rel + (size_t)i * 64, rel_text_init, N);
        k_update<<<gb_upd_t, 256, 0, stream>>>(
            text_W + (size_t)i * 128 * 64, text_b + i * 64,
            text_g + i * 64, text_beta + i * 64, x_t, agg_t, N);
    }

    // ---- fusion ----
    k_fuse<<<gb_upd_s, 256, 0, stream>>>(
        fuse_W1, fuse_b1, fuse_W2, fuse_b2, x_s, x_t, N, rows_s);
}

// Round 5
// 1674.597 us; speedup vs baseline: 4.3710x; 1.0313x over previous
//
#include <hip/hip_runtime.h>

// ---------------------------------------------------------------------------
// SemmaRelModel: two 6-layer NBFNet branches + MLP fusion.
// Round 5: kill scratch-resident accumulators in k_update/k_fuse.
//   Round-4 evidence: VGPR_Count=68 (< acc[64]!) + 40MB extra FETCH/WRITE
//   -> local arrays went to scratch (address-taken via float4 casts).
//   Now: named float4 registers A0..A15 / O0..O3, no local arrays at all.
// ---------------------------------------------------------------------------

// ---- named-register macro kit (A0..A15 / O0..O3 must be in scope) ----
#define FMA16(v, wbase) do {                                                  \
    const float4* _w = (const float4*)(wbase); float4 _t;                     \
    _t=_w[0];  A0.x=fmaf(v,_t.x,A0.x);  A0.y=fmaf(v,_t.y,A0.y);  A0.z=fmaf(v,_t.z,A0.z);  A0.w=fmaf(v,_t.w,A0.w);   \
    _t=_w[1];  A1.x=fmaf(v,_t.x,A1.x);  A1.y=fmaf(v,_t.y,A1.y);  A1.z=fmaf(v,_t.z,A1.z);  A1.w=fmaf(v,_t.w,A1.w);   \
    _t=_w[2];  A2.x=fmaf(v,_t.x,A2.x);  A2.y=fmaf(v,_t.y,A2.y);  A2.z=fmaf(v,_t.z,A2.z);  A2.w=fmaf(v,_t.w,A2.w);   \
    _t=_w[3];  A3.x=fmaf(v,_t.x,A3.x);  A3.y=fmaf(v,_t.y,A3.y);  A3.z=fmaf(v,_t.z,A3.z);  A3.w=fmaf(v,_t.w,A3.w);   \
    _t=_w[4];  A4.x=fmaf(v,_t.x,A4.x);  A4.y=fmaf(v,_t.y,A4.y);  A4.z=fmaf(v,_t.z,A4.z);  A4.w=fmaf(v,_t.w,A4.w);   \
    _t=_w[5];  A5.x=fmaf(v,_t.x,A5.x);  A5.y=fmaf(v,_t.y,A5.y);  A5.z=fmaf(v,_t.z,A5.z);  A5.w=fmaf(v,_t.w,A5.w);   \
    _t=_w[6];  A6.x=fmaf(v,_t.x,A6.x);  A6.y=fmaf(v,_t.y,A6.y);  A6.z=fmaf(v,_t.z,A6.z);  A6.w=fmaf(v,_t.w,A6.w);   \
    _t=_w[7];  A7.x=fmaf(v,_t.x,A7.x);  A7.y=fmaf(v,_t.y,A7.y);  A7.z=fmaf(v,_t.z,A7.z);  A7.w=fmaf(v,_t.w,A7.w);   \
    _t=_w[8];  A8.x=fmaf(v,_t.x,A8.x);  A8.y=fmaf(v,_t.y,A8.y);  A8.z=fmaf(v,_t.z,A8.z);  A8.w=fmaf(v,_t.w,A8.w);   \
    _t=_w[9];  A9.x=fmaf(v,_t.x,A9.x);  A9.y=fmaf(v,_t.y,A9.y);  A9.z=fmaf(v,_t.z,A9.z);  A9.w=fmaf(v,_t.w,A9.w);   \
    _t=_w[10]; A10.x=fmaf(v,_t.x,A10.x); A10.y=fmaf(v,_t.y,A10.y); A10.z=fmaf(v,_t.z,A10.z); A10.w=fmaf(v,_t.w,A10.w); \
    _t=_w[11]; A11.x=fmaf(v,_t.x,A11.x); A11.y=fmaf(v,_t.y,A11.y); A11.z=fmaf(v,_t.z,A11.z); A11.w=fmaf(v,_t.w,A11.w); \
    _t=_w[12]; A12.x=fmaf(v,_t.x,A12.x); A12.y=fmaf(v,_t.y,A12.y); A12.z=fmaf(v,_t.z,A12.z); A12.w=fmaf(v,_t.w,A12.w); \
    _t=_w[13]; A13.x=fmaf(v,_t.x,A13.x); A13.y=fmaf(v,_t.y,A13.y); A13.z=fmaf(v,_t.z,A13.z); A13.w=fmaf(v,_t.w,A13.w); \
    _t=_w[14]; A14.x=fmaf(v,_t.x,A14.x); A14.y=fmaf(v,_t.y,A14.y); A14.z=fmaf(v,_t.z,A14.z); A14.w=fmaf(v,_t.w,A14.w); \
    _t=_w[15]; A15.x=fmaf(v,_t.x,A15.x); A15.y=fmaf(v,_t.y,A15.y); A15.z=fmaf(v,_t.z,A15.z); A15.w=fmaf(v,_t.w,A15.w); \
} while (0)

#define FMA4O(v, wbase) do {                                                  \
    const float4* _w = (const float4*)(wbase); float4 _t;                     \
    _t=_w[0]; O0.x=fmaf(v,_t.x,O0.x); O0.y=fmaf(v,_t.y,O0.y); O0.z=fmaf(v,_t.z,O0.z); O0.w=fmaf(v,_t.w,O0.w); \
    _t=_w[1]; O1.x=fmaf(v,_t.x,O1.x); O1.y=fmaf(v,_t.y,O1.y); O1.z=fmaf(v,_t.z,O1.z); O1.w=fmaf(v,_t.w,O1.w); \
    _t=_w[2]; O2.x=fmaf(v,_t.x,O2.x); O2.y=fmaf(v,_t.y,O2.y); O2.z=fmaf(v,_t.z,O2.z); O2.w=fmaf(v,_t.w,O2.w); \
    _t=_w[3]; O3.x=fmaf(v,_t.x,O3.x); O3.y=fmaf(v,_t.y,O3.y); O3.z=fmaf(v,_t.z,O3.z); O3.w=fmaf(v,_t.w,O3.w); \
} while (0)

#define SUM4(Ai) ((Ai.x + Ai.y) + (Ai.z + Ai.w))
#define VAR4(Ai) do { float _c;                                               \
    _c = Ai.x - m; vs = fmaf(_c, _c, vs); _c = Ai.y - m; vs = fmaf(_c, _c, vs); \
    _c = Ai.z - m; vs = fmaf(_c, _c, vs); _c = Ai.w - m; vs = fmaf(_c, _c, vs); \
} while (0)

// x[idx] = (n == h_index[b]) ? 1 : 0   over [B,N,64]
__global__ __launch_bounds__(256) void k_init_onehot(
    float* __restrict__ x, const int* __restrict__ h_index, int N, int total)
{
    int idx = blockIdx.x * 256 + threadIdx.x;
    if (idx >= total) return;
    int row = idx >> 6;
    int b = row / N;
    int n = row - b * N;
    x[idx] = (n == h_index[b]) ? 1.0f : 0.0f;
}

// ---- CSR build ----
__global__ __launch_bounds__(256) void k_hist(
    const int* __restrict__ dst, int* __restrict__ cnt, int E)
{
    int e = blockIdx.x * 256 + threadIdx.x;
    if (e < E) atomicAdd(&cnt[dst[e]], 1);
}

__global__ __launch_bounds__(1024) void k_scan(
    const int* __restrict__ cnt, int* __restrict__ off, int n)
{
    __shared__ int wpre[16];
    __shared__ int total_s;
    __shared__ int carry_s;
    int tid = threadIdx.x, lane = tid & 63, w = tid >> 6;
    if (tid == 0) { carry_s = 0; off[0] = 0; }
    __syncthreads();
    for (int base = 0; base < n; base += 1024) {
        int i = base + tid;
        int v = (i < n) ? cnt[i] : 0;
        int s = v;
        #pragma unroll
        for (int d = 1; d < 64; d <<= 1) {
            int t = __shfl_up(s, d);
            if (lane >= d) s += t;
        }
        __shared__ int wsum[16];
        if (lane == 63) wsum[w] = s;
        __syncthreads();
        if (w == 0 && lane < 16) {
            int ws = wsum[lane];
            int p = ws;
            #pragma unroll
            for (int d = 1; d < 16; d <<= 1) {
                int t = __shfl_up(p, d);
                if (lane >= d) p += t;
            }
            wpre[lane] = p - ws;
            if (lane == 15) total_s = p;
        }
        __syncthreads();
        int carry = carry_s;
        if (i < n) off[i + 1] = carry + wpre[w] + s;
        __syncthreads();
        if (tid == 0) carry_s = carry + total_s;
        __syncthreads();
    }
}

__global__ __launch_bounds__(256) void k_fill(
    const int* __restrict__ src, const int* __restrict__ dst,
    const int* __restrict__ etype,
    const int* __restrict__ off, int* __restrict__ cnt,
    int* __restrict__ packed, int E)
{
    int e = blockIdx.x * 256 + threadIdx.x;
    if (e >= E) return;
    int d = dst[e];
    int pos = off[d] + atomicSub(&cnt[d], 1) - 1;
    int ty = etype ? etype[e] : 0;
    packed[pos] = src[e] | (ty << 27);
}

// ---- aggregation: one wave per (b,n); lane = dim ----
__global__ __launch_bounds__(256) void k_gather_struct(
    const float* __restrict__ x, float* __restrict__ agg,
    const int* __restrict__ off, const int* __restrict__ packed,
    const float* __restrict__ rel,       // [4,64]
    const int* __restrict__ h_index,
    int N, int BN)
{
    int wid = (blockIdx.x * 256 + threadIdx.x) >> 6;
    int lane = threadIdx.x & 63;
    if (wid >= BN) return;
    int b = wid / N;
    int n = wid - b * N;
    float r0 = rel[0 * 64 + lane], r1 = rel[1 * 64 + lane];
    float r2 = rel[2 * 64 + lane], r3 = rel[3 * 64 + lane];
    const float* xb = x + (size_t)b * N * 64;
    float acc = (n == h_index[b]) ? 1.0f : 0.0f;
    int p0 = off[n], p1 = off[n + 1];
    for (int p = p0; p < p1; ++p) {
        int pk = packed[p];
        int s = pk & 0x03FFFFFF;
        int ty = pk >> 27;
        float r = (ty < 2) ? (ty == 0 ? r0 : r1) : (ty == 2 ? r2 : r3);
        acc += xb[(size_t)s * 64 + lane] * r;
    }
    agg[(size_t)wid * 64 + lane] = acc;
}

__global__ __launch_bounds__(256) void k_gather_text(
    const float* __restrict__ x, float* __restrict__ agg,
    const int* __restrict__ off, const int* __restrict__ packed,
    const float* __restrict__ rel,       // [64]
    const float* __restrict__ init,      // [N,64]
    int N)
{
    int wid = (blockIdx.x * 256 + threadIdx.x) >> 6;
    int lane = threadIdx.x & 63;
    if (wid >= N) return;
    float r = rel[lane];
    float acc = init[(size_t)wid * 64 + lane];
    int p0 = off[wid], p1 = off[wid + 1];
    for (int p = p0; p < p1; ++p) {
        int s = packed[p];
        acc += x[(size_t)s * 64 + lane] * r;
    }
    agg[(size_t)wid * 64 + lane] = acc;
}

// ---- dense update: one THREAD per row, acc in 16 named float4 regs ----
// x_row = relu(LN(concat(x_row, agg_row) @ W + b)) + x_row   (in place)
__global__ __launch_bounds__(256) void k_update(
    const float* __restrict__ W,      // [128,64]
    const float* __restrict__ bias, const float* __restrict__ g,
    const float* __restrict__ beta,
    float* __restrict__ x, const float* __restrict__ agg, int rows)
{
    __shared__ float Wl[128 * 64];
    __shared__ float bl[64], gl[64], bel[64];
    int tid = threadIdx.x;
    {
        const float4* W4 = (const float4*)W;
        float4* Wl4 = (float4*)Wl;
        #pragma unroll
        for (int i = 0; i < 8; ++i) Wl4[tid + i * 256] = W4[tid + i * 256];
        if (tid < 64) { bl[tid] = bias[tid]; gl[tid] = g[tid]; bel[tid] = beta[tid]; }
    }
    __syncthreads();

    int row = blockIdx.x * 256 + tid;
    if (row >= rows) return;
    const float* xr = x + (size_t)row * 64;
    const float* ar = agg + (size_t)row * 64;

    const float4* bl4 = (const float4*)bl;
    float4 A0 = bl4[0],  A1 = bl4[1],  A2 = bl4[2],  A3 = bl4[3];
    float4 A4 = bl4[4],  A5 = bl4[5],  A6 = bl4[6],  A7 = bl4[7];
    float4 A8 = bl4[8],  A9 = bl4[9],  A10 = bl4[10], A11 = bl4[11];
    float4 A12 = bl4[12], A13 = bl4[13], A14 = bl4[14], A15 = bl4[15];

    #pragma unroll
    for (int kc = 0; kc < 64; kc += 4) {
        float4 iv = *(const float4*)(xr + kc);
        FMA16(iv.x, Wl + (kc + 0) * 64);
        FMA16(iv.y, Wl + (kc + 1) * 64);
        FMA16(iv.z, Wl + (kc + 2) * 64);
        FMA16(iv.w, Wl + (kc + 3) * 64);
    }
    #pragma unroll
    for (int kc = 0; kc < 64; kc += 4) {
        float4 iv = *(const float4*)(ar + kc);
        FMA16(iv.x, Wl + (64 + kc + 0) * 64);
        FMA16(iv.y, Wl + (64 + kc + 1) * 64);
        FMA16(iv.z, Wl + (64 + kc + 2) * 64);
        FMA16(iv.w, Wl + (64 + kc + 3) * 64);
    }

    // LayerNorm + relu + residual, all in registers
    float s = SUM4(A0) + SUM4(A1) + SUM4(A2) + SUM4(A3)
            + SUM4(A4) + SUM4(A5) + SUM4(A6) + SUM4(A7)
            + SUM4(A8) + SUM4(A9) + SUM4(A10) + SUM4(A11)
            + SUM4(A12) + SUM4(A13) + SUM4(A14) + SUM4(A15);
    float m = s * (1.0f / 64.0f);
    float vs = 0.f;
    VAR4(A0);  VAR4(A1);  VAR4(A2);  VAR4(A3);
    VAR4(A4);  VAR4(A5);  VAR4(A6);  VAR4(A7);
    VAR4(A8);  VAR4(A9);  VAR4(A10); VAR4(A11);
    VAR4(A12); VAR4(A13); VAR4(A14); VAR4(A15);
    float inv = rsqrtf(vs * (1.0f / 64.0f) + 1e-5f);

    float* xw = x + (size_t)row * 64;
    #define OUT4(Aj, J) do {                                                  \
        float4 xv = ((const float4*)xr)[J];                                   \
        float4 gg = ((const float4*)gl)[J];                                   \
        float4 bb = ((const float4*)bel)[J];                                  \
        float4 y;                                                             \
        y.x = fmaxf((Aj.x - m) * inv * gg.x + bb.x, 0.f) + xv.x;              \
        y.y = fmaxf((Aj.y - m) * inv * gg.y + bb.y, 0.f) + xv.y;              \
        y.z = fmaxf((Aj.z - m) * inv * gg.z + bb.z, 0.f) + xv.z;              \
        y.w = fmaxf((Aj.w - m) * inv * gg.w + bb.w, 0.f) + xv.w;              \
        ((float4*)xw)[J] = y; } while (0)
    OUT4(A0, 0);   OUT4(A1, 1);   OUT4(A2, 2);   OUT4(A3, 3);
    OUT4(A4, 4);   OUT4(A5, 5);   OUT4(A6, 6);   OUT4(A7, 7);
    OUT4(A8, 8);   OUT4(A9, 9);   OUT4(A10, 10); OUT4(A11, 11);
    OUT4(A12, 12); OUT4(A13, 13); OUT4(A14, 14); OUT4(A15, 15);
    #undef OUT4
}

// ---- fusion: one THREAD per row; all accumulators in named regs ----
// out_row = relu(concat(h_row, z_row) @ W1 + b1) @ W2 + b2  (in place on out=h)
__global__ __launch_bounds__(256) void k_fuse(
    const float* __restrict__ W1, const float* __restrict__ b1,
    const float* __restrict__ W2, const float* __restrict__ b2,
    float* __restrict__ out, const float* __restrict__ z, int N, int rows)
{
    __shared__ float W1l[128 * 64];
    __shared__ float W2l[64 * 64];
    __shared__ float b1l[64], b2l[64];
    int tid = threadIdx.x;
    {
        const float4* Wa = (const float4*)W1;
        float4* Wla = (float4*)W1l;
        #pragma unroll
        for (int i = 0; i < 8; ++i) Wla[tid + i * 256] = Wa[tid + i * 256];
        const float4* Wb = (const float4*)W2;
        float4* Wlb = (float4*)W2l;
        #pragma unroll
        for (int i = 0; i < 4; ++i) Wlb[tid + i * 256] = Wb[tid + i * 256];
        if (tid < 64) { b1l[tid] = b1[tid]; b2l[tid] = b2[tid]; }
    }
    __syncthreads();

    int row = blockIdx.x * 256 + tid;
    if (row >= rows) return;
    int n = row % N;
    const float* hr = out + (size_t)row * 64;
    const float* zr = z + (size_t)n * 64;

    // first GEMV: A = relu(concat(h,z) @ W1 + b1)
    const float4* b1l4 = (const float4*)b1l;
    float4 A0 = b1l4[0],  A1 = b1l4[1],  A2 = b1l4[2],  A3 = b1l4[3];
    float4 A4 = b1l4[4],  A5 = b1l4[5],  A6 = b1l4[6],  A7 = b1l4[7];
    float4 A8 = b1l4[8],  A9 = b1l4[9],  A10 = b1l4[10], A11 = b1l4[11];
    float4 A12 = b1l4[12], A13 = b1l4[13], A14 = b1l4[14], A15 = b1l4[15];

    #pragma unroll
    for (int kc = 0; kc < 64; kc += 4) {
        float4 iv = *(const float4*)(hr + kc);
        FMA16(iv.x, W1l + (kc + 0) * 64);
        FMA16(iv.y, W1l + (kc + 1) * 64);
        FMA16(iv.z, W1l + (kc + 2) * 64);
        FMA16(iv.w, W1l + (kc + 3) * 64);
    }
    #pragma unroll
    for (int kc = 0; kc < 64; kc += 4) {
        float4 iv = *(const float4*)(zr + kc);
        FMA16(iv.x, W1l + (64 + kc + 0) * 64);
        FMA16(iv.y, W1l + (64 + kc + 1) * 64);
        FMA16(iv.z, W1l + (64 + kc + 2) * 64);
        FMA16(iv.w, W1l + (64 + kc + 3) * 64);
    }
    #define RELU4(Ai) do { Ai.x = fmaxf(Ai.x, 0.f); Ai.y = fmaxf(Ai.y, 0.f); \
                           Ai.z = fmaxf(Ai.z, 0.f); Ai.w = fmaxf(Ai.w, 0.f); } while (0)
    RELU4(A0);  RELU4(A1);  RELU4(A2);  RELU4(A3);
    RELU4(A4);  RELU4(A5);  RELU4(A6);  RELU4(A7);
    RELU4(A8);  RELU4(A9);  RELU4(A10); RELU4(A11);
    RELU4(A12); RELU4(A13); RELU4(A14); RELU4(A15);
    #undef RELU4

    // second GEMV in 4 chunks of 16 outputs (O0..O3 live per chunk)
    float* ow = out + (size_t)row * 64;
    #pragma unroll
    for (int jc = 0; jc < 64; jc += 16) {
        const float4* bb4 = (const float4*)(b2l + jc);
        float4 O0 = bb4[0], O1 = bb4[1], O2 = bb4[2], O3 = bb4[3];
        #define KS(Ai, kb) do {                                               \
            FMA4O(Ai.x, W2l + (kb + 0) * 64 + jc);                            \
            FMA4O(Ai.y, W2l + (kb + 1) * 64 + jc);                            \
            FMA4O(Ai.z, W2l + (kb + 2) * 64 + jc);                            \
            FMA4O(Ai.w, W2l + (kb + 3) * 64 + jc); } while (0)
        KS(A0, 0);   KS(A1, 4);   KS(A2, 8);   KS(A3, 12);
        KS(A4, 16);  KS(A5, 20);  KS(A6, 24);  KS(A7, 28);
        KS(A8, 32);  KS(A9, 36);  KS(A10, 40); KS(A11, 44);
        KS(A12, 48); KS(A13, 52); KS(A14, 56); KS(A15, 60);
        #undef KS
        float4* ow4 = (float4*)(ow + jc);
        ow4[0] = O0; ow4[1] = O1; ow4[2] = O2; ow4[3] = O3;
    }
}

extern "C" void kernel_launch(void* const* d_in, const int* in_sizes, int n_in,
                              void* d_out, int out_size, void* d_ws, size_t ws_size,
                              hipStream_t stream)
{
    const float* rel_text_init = (const float*)d_in[0];
    const float* struct_rel    = (const float*)d_in[1];
    const float* struct_W      = (const float*)d_in[2];
    const float* struct_b      = (const float*)d_in[3];
    const float* struct_g      = (const float*)d_in[4];
    const float* struct_beta   = (const float*)d_in[5];
    const float* text_rel      = (const float*)d_in[6];
    const float* text_W        = (const float*)d_in[7];
    const float* text_b        = (const float*)d_in[8];
    const float* text_g        = (const float*)d_in[9];
    const float* text_beta     = (const float*)d_in[10];
    const float* fuse_W1       = (const float*)d_in[11];
    const float* fuse_b1       = (const float*)d_in[12];
    const float* fuse_W2       = (const float*)d_in[13];
    const float* fuse_b2       = (const float*)d_in[14];
    const int*   h_index       = (const int*)d_in[15];
    const int*   edge_index    = (const int*)d_in[16];
    const int*   edge_type     = (const int*)d_in[17];
    const int*   text_edge_idx = (const int*)d_in[18];

    const int B  = in_sizes[15];
    const int N  = in_sizes[0] / 64;
    const int E  = in_sizes[17];
    const int ET = in_sizes[18] / 2;
    const int L  = in_sizes[3] / 64;
    const int R  = in_sizes[1] / (L * 64);

    const int* src  = edge_index;
    const int* dst  = edge_index + E;
    const int* tsrc = text_edge_idx;
    const int* tdst = text_edge_idx + ET;

    // ---- workspace layout ----
    float* x_t   = (float*)d_ws;                     // [N,64]
    float* agg_t = x_t + (size_t)N * 64;             // [N,64]
    float* agg_s = agg_t + (size_t)N * 64;           // [B,N,64]
    int*   cnt_s = (int*)(agg_s + (size_t)B * N * 64);  // [N]
    int*   off_s = cnt_s + N;                        // [N+1]
    int*   pk_s  = off_s + N + 1;                    // [E]
    int*   cnt_t = pk_s + E;                         // [N]
    int*   off_t = cnt_t + N;                        // [N+1]
    int*   pk_t  = off_t + N + 1;                    // [ET]

    float* x_s = (float*)d_out;                      // [B,N,64]

    const size_t nd  = (size_t)N * 64;
    const int rows_s = B * N;
    const int tot_s  = rows_s * 64;

    const int gb_init   = (tot_s + 255) / 256;
    const int gb_e      = (E + 255) / 256;
    const int gb_et     = (ET + 255) / 256;
    const int gb_gath_s = (rows_s * 64 + 255) / 256;
    const int gb_gath_t = ((int)nd + 255) / 256;
    const int gb_upd_s  = (rows_s + 255) / 256;
    const int gb_upd_t  = (N + 255) / 256;

    // ---- CSR builds ----
    hipMemsetAsync(cnt_s, 0, (size_t)N * 4, stream);
    hipMemsetAsync(cnt_t, 0, (size_t)N * 4, stream);
    k_hist<<<gb_e, 256, 0, stream>>>(dst, cnt_s, E);
    k_hist<<<gb_et, 256, 0, stream>>>(tdst, cnt_t, ET);
    k_scan<<<1, 1024, 0, stream>>>(cnt_s, off_s, N);
    k_scan<<<1, 1024, 0, stream>>>(cnt_t, off_t, N);
    k_fill<<<gb_e, 256, 0, stream>>>(src, dst, edge_type, off_s, cnt_s, pk_s, E);
    k_fill<<<gb_et, 256, 0, stream>>>(tsrc, tdst, nullptr, off_t, cnt_t, pk_t, ET);

    // ---- struct branch (state in d_out) ----
    k_init_onehot<<<gb_init, 256, 0, stream>>>(x_s, h_index, N, tot_s);
    for (int i = 0; i < L; ++i) {
        k_gather_struct<<<gb_gath_s, 256, 0, stream>>>(
            x_s, agg_s, off_s, pk_s,
            struct_rel + (size_t)i * R * 64, h_index, N, rows_s);
        k_update<<<gb_upd_s, 256, 0, stream>>>(
            struct_W + (size_t)i * 128 * 64, struct_b + i * 64,
            struct_g + i * 64, struct_beta + i * 64, x_s, agg_s, rows_s);
    }

    // ---- text branch (batch-invariant) ----
    hipMemcpyAsync(x_t, rel_text_init, nd * sizeof(float),
                   hipMemcpyDeviceToDevice, stream);
    for (int i = 0; i < L; ++i) {
        k_gather_text<<<gb_gath_t, 256, 0, stream>>>(
            x_t, agg_t, off_t, pk_t,
            text_rel + (size_t)i * 64, rel_text_init, N);
        k_update<<<gb_upd_t, 256, 0, stream>>>(
            text_W + (size_t)i * 128 * 64, text_b + i * 64,
            text_g + i * 64, text_beta + i * 64, x_t, agg_t, N);
    }

    // ---- fusion ----
    k_fuse<<<gb_upd_s, 256, 0, stream>>>(
        fuse_W1, fuse_b1, fuse_W2, fuse_b2, x_s, x_t, N, rows_s);
}

// Round 6
// 863.675 us; speedup vs baseline: 8.4749x; 1.9389x over previous
//
#include <hip/hip_runtime.h>

// ---------------------------------------------------------------------------
// SemmaRelModel: two 6-layer NBFNet branches + MLP fusion.
// Round 6:
//  - k_gather_struct: wave-per-node, BOTH batches per wave, 4-edge unroll
//    (8 loads in flight), scalarized CSR metadata. (was latency-bound: 27%
//    VALU, 16% HBM, 1 load in flight)
//  - k_update: 4 threads/row x 16 outputs (was 1.5 waves/SIMD work-starved);
//    LN partial sums combined with __shfl_xor(1|2) in the 4-lane group.
// ---------------------------------------------------------------------------

// ---- macro kit ----
#define FMA4R(v, wbase, R0, R1, R2, R3) do {                                  \
    const float4* _w = (const float4*)(wbase); float4 _t;                     \
    _t=_w[0]; R0.x=fmaf(v,_t.x,R0.x); R0.y=fmaf(v,_t.y,R0.y); R0.z=fmaf(v,_t.z,R0.z); R0.w=fmaf(v,_t.w,R0.w); \
    _t=_w[1]; R1.x=fmaf(v,_t.x,R1.x); R1.y=fmaf(v,_t.y,R1.y); R1.z=fmaf(v,_t.z,R1.z); R1.w=fmaf(v,_t.w,R1.w); \
    _t=_w[2]; R2.x=fmaf(v,_t.x,R2.x); R2.y=fmaf(v,_t.y,R2.y); R2.z=fmaf(v,_t.z,R2.z); R2.w=fmaf(v,_t.w,R2.w); \
    _t=_w[3]; R3.x=fmaf(v,_t.x,R3.x); R3.y=fmaf(v,_t.y,R3.y); R3.z=fmaf(v,_t.z,R3.z); R3.w=fmaf(v,_t.w,R3.w); \
} while (0)

#define FMA16(v, wbase) do {                                                  \
    FMA4R(v, (wbase),      A0, A1, A2, A3);                                   \
    FMA4R(v, (wbase) + 16, A4, A5, A6, A7);                                   \
    FMA4R(v, (wbase) + 32, A8, A9, A10, A11);                                 \
    FMA4R(v, (wbase) + 48, A12, A13, A14, A15);                               \
} while (0)

#define SUM4(Ai) ((Ai.x + Ai.y) + (Ai.z + Ai.w))
#define VAR4(Ai) do { float _c;                                               \
    _c = Ai.x - m; vs = fmaf(_c, _c, vs); _c = Ai.y - m; vs = fmaf(_c, _c, vs); \
    _c = Ai.z - m; vs = fmaf(_c, _c, vs); _c = Ai.w - m; vs = fmaf(_c, _c, vs); \
} while (0)

// x[idx] = (n == h_index[b]) ? 1 : 0   over [B,N,64]
__global__ __launch_bounds__(256) void k_init_onehot(
    float* __restrict__ x, const int* __restrict__ h_index, int N, int total)
{
    int idx = blockIdx.x * 256 + threadIdx.x;
    if (idx >= total) return;
    int row = idx >> 6;
    int b = row / N;
    int n = row - b * N;
    x[idx] = (n == h_index[b]) ? 1.0f : 0.0f;
}

// ---- CSR build ----
__global__ __launch_bounds__(256) void k_hist(
    const int* __restrict__ dst, int* __restrict__ cnt, int E)
{
    int e = blockIdx.x * 256 + threadIdx.x;
    if (e < E) atomicAdd(&cnt[dst[e]], 1);
}

__global__ __launch_bounds__(1024) void k_scan(
    const int* __restrict__ cnt, int* __restrict__ off, int n)
{
    __shared__ int wpre[16];
    __shared__ int total_s;
    __shared__ int carry_s;
    int tid = threadIdx.x, lane = tid & 63, w = tid >> 6;
    if (tid == 0) { carry_s = 0; off[0] = 0; }
    __syncthreads();
    for (int base = 0; base < n; base += 1024) {
        int i = base + tid;
        int v = (i < n) ? cnt[i] : 0;
        int s = v;
        #pragma unroll
        for (int d = 1; d < 64; d <<= 1) {
            int t = __shfl_up(s, d);
            if (lane >= d) s += t;
        }
        __shared__ int wsum[16];
        if (lane == 63) wsum[w] = s;
        __syncthreads();
        if (w == 0 && lane < 16) {
            int ws = wsum[lane];
            int p = ws;
            #pragma unroll
            for (int d = 1; d < 16; d <<= 1) {
                int t = __shfl_up(p, d);
                if (lane >= d) p += t;
            }
            wpre[lane] = p - ws;
            if (lane == 15) total_s = p;
        }
        __syncthreads();
        int carry = carry_s;
        if (i < n) off[i + 1] = carry + wpre[w] + s;
        __syncthreads();
        if (tid == 0) carry_s = carry + total_s;
        __syncthreads();
    }
}

__global__ __launch_bounds__(256) void k_fill(
    const int* __restrict__ src, const int* __restrict__ dst,
    const int* __restrict__ etype,
    const int* __restrict__ off, int* __restrict__ cnt,
    int* __restrict__ packed, int E)
{
    int e = blockIdx.x * 256 + threadIdx.x;
    if (e >= E) return;
    int d = dst[e];
    int pos = off[d] + atomicSub(&cnt[d], 1) - 1;
    int ty = etype ? etype[e] : 0;
    packed[pos] = src[e] | (ty << 27);
}

// ---- struct aggregation: one wave per node n, BOTH batches ----
__global__ __launch_bounds__(256) void k_gather_struct2(
    const float* __restrict__ x, float* __restrict__ agg,
    const int* __restrict__ off, const int* __restrict__ packed,
    const float* __restrict__ rel,       // [4,64]
    const int* __restrict__ h_index,
    int N)
{
    int n = (blockIdx.x * 256 + threadIdx.x) >> 6;
    int lane = threadIdx.x & 63;
    if (n >= N) return;
    float r0 = rel[lane], r1 = rel[64 + lane];
    float r2 = rel[128 + lane], r3 = rel[192 + lane];
    const float* x0 = x;
    const float* x1 = x + (size_t)N * 64;
    float acc0 = (n == h_index[0]) ? 1.0f : 0.0f;
    float acc1 = (n == h_index[1]) ? 1.0f : 0.0f;
    int p0 = __builtin_amdgcn_readfirstlane(off[n]);
    int p1 = __builtin_amdgcn_readfirstlane(off[n + 1]);
    int p = p0;
    for (; p + 4 <= p1; p += 4) {
        int pka = __builtin_amdgcn_readfirstlane(packed[p + 0]);
        int pkb = __builtin_amdgcn_readfirstlane(packed[p + 1]);
        int pkc = __builtin_amdgcn_readfirstlane(packed[p + 2]);
        int pkd = __builtin_amdgcn_readfirstlane(packed[p + 3]);
        int sa = pka & 0x03FFFFFF, ta = pka >> 27;
        int sb = pkb & 0x03FFFFFF, tb = pkb >> 27;
        int sc = pkc & 0x03FFFFFF, tc = pkc >> 27;
        int sd = pkd & 0x03FFFFFF, td = pkd >> 27;
        float ra = (ta < 2) ? (ta == 0 ? r0 : r1) : (ta == 2 ? r2 : r3);
        float rb = (tb < 2) ? (tb == 0 ? r0 : r1) : (tb == 2 ? r2 : r3);
        float rc = (tc < 2) ? (tc == 0 ? r0 : r1) : (tc == 2 ? r2 : r3);
        float rd = (td < 2) ? (td == 0 ? r0 : r1) : (td == 2 ? r2 : r3);
        float a0 = x0[(size_t)sa * 64 + lane], a1 = x1[(size_t)sa * 64 + lane];
        float b0 = x0[(size_t)sb * 64 + lane], b1 = x1[(size_t)sb * 64 + lane];
        float c0 = x0[(size_t)sc * 64 + lane], c1 = x1[(size_t)sc * 64 + lane];
        float d0 = x0[(size_t)sd * 64 + lane], d1 = x1[(size_t)sd * 64 + lane];
        acc0 = fmaf(a0, ra, acc0); acc1 = fmaf(a1, ra, acc1);
        acc0 = fmaf(b0, rb, acc0); acc1 = fmaf(b1, rb, acc1);
        acc0 = fmaf(c0, rc, acc0); acc1 = fmaf(c1, rc, acc1);
        acc0 = fmaf(d0, rd, acc0); acc1 = fmaf(d1, rd, acc1);
    }
    for (; p < p1; ++p) {
        int pk = __builtin_amdgcn_readfirstlane(packed[p]);
        int s = pk & 0x03FFFFFF, ty = pk >> 27;
        float r = (ty < 2) ? (ty == 0 ? r0 : r1) : (ty == 2 ? r2 : r3);
        float v0 = x0[(size_t)s * 64 + lane], v1 = x1[(size_t)s * 64 + lane];
        acc0 = fmaf(v0, r, acc0); acc1 = fmaf(v1, r, acc1);
    }
    agg[(size_t)n * 64 + lane] = acc0;
    agg[(size_t)(N + n) * 64 + lane] = acc1;
}

// generic fallback (B != 2), one wave per (b,n)
__global__ __launch_bounds__(256) void k_gather_struct_gen(
    const float* __restrict__ x, float* __restrict__ agg,
    const int* __restrict__ off, const int* __restrict__ packed,
    const float* __restrict__ rel, const int* __restrict__ h_index,
    int N, int BN)
{
    int wid = (blockIdx.x * 256 + threadIdx.x) >> 6;
    int lane = threadIdx.x & 63;
    if (wid >= BN) return;
    int b = wid / N;
    int n = wid - b * N;
    float r0 = rel[lane], r1 = rel[64 + lane];
    float r2 = rel[128 + lane], r3 = rel[192 + lane];
    const float* xb = x + (size_t)b * N * 64;
    float acc = (n == h_index[b]) ? 1.0f : 0.0f;
    int p0 = off[n], p1 = off[n + 1];
    for (int p = p0; p < p1; ++p) {
        int pk = packed[p];
        int s = pk & 0x03FFFFFF, ty = pk >> 27;
        float r = (ty < 2) ? (ty == 0 ? r0 : r1) : (ty == 2 ? r2 : r3);
        acc = fmaf(xb[(size_t)s * 64 + lane], r, acc);
    }
    agg[(size_t)wid * 64 + lane] = acc;
}

// ---- text aggregation: one wave per node, 4-edge unroll ----
__global__ __launch_bounds__(256) void k_gather_text(
    const float* __restrict__ x, float* __restrict__ agg,
    const int* __restrict__ off, const int* __restrict__ packed,
    const float* __restrict__ rel,       // [64]
    const float* __restrict__ init,      // [N,64]
    int N)
{
    int n = (blockIdx.x * 256 + threadIdx.x) >> 6;
    int lane = threadIdx.x & 63;
    if (n >= N) return;
    float r = rel[lane];
    float acc = init[(size_t)n * 64 + lane];
    int p0 = __builtin_amdgcn_readfirstlane(off[n]);
    int p1 = __builtin_amdgcn_readfirstlane(off[n + 1]);
    int p = p0;
    float acc2 = 0.f;
    for (; p + 4 <= p1; p += 4) {
        int sa = __builtin_amdgcn_readfirstlane(packed[p + 0]);
        int sb = __builtin_amdgcn_readfirstlane(packed[p + 1]);
        int sc = __builtin_amdgcn_readfirstlane(packed[p + 2]);
        int sd = __builtin_amdgcn_readfirstlane(packed[p + 3]);
        float a = x[(size_t)sa * 64 + lane];
        float b = x[(size_t)sb * 64 + lane];
        float c = x[(size_t)sc * 64 + lane];
        float d = x[(size_t)sd * 64 + lane];
        acc = fmaf(a, r, acc);  acc2 = fmaf(b, r, acc2);
        acc = fmaf(c, r, acc);  acc2 = fmaf(d, r, acc2);
    }
    for (; p < p1; ++p) {
        int s = __builtin_amdgcn_readfirstlane(packed[p]);
        acc = fmaf(x[(size_t)s * 64 + lane], r, acc);
    }
    agg[(size_t)n * 64 + lane] = acc + acc2;
}

// ---- dense update: 4 threads per row, 16 outputs each ----
// x_row = relu(LN(concat(x_row, agg_row) @ W + b)) + x_row   (in place)
__global__ __launch_bounds__(256) void k_update(
    const float* __restrict__ W,      // [128,64]
    const float* __restrict__ bias, const float* __restrict__ g,
    const float* __restrict__ beta,
    float* __restrict__ x, const float* __restrict__ agg, int rows)
{
    __shared__ float Wl[128 * 64];
    __shared__ float bl[64], gl[64], bel[64];
    int tid = threadIdx.x;
    {
        const float4* W4 = (const float4*)W;
        float4* Wl4 = (float4*)Wl;
        #pragma unroll
        for (int i = 0; i < 8; ++i) Wl4[tid + i * 256] = W4[tid + i * 256];
        if (tid < 64) { bl[tid] = bias[tid]; gl[tid] = g[tid]; bel[tid] = beta[tid]; }
    }
    __syncthreads();

    int gt = blockIdx.x * 256 + tid;
    int row = gt >> 2;              // 4 threads share a row
    int jc = (gt & 3) * 16;         // this thread's output chunk
    if (row >= rows) return;
    const float* xr = x + (size_t)row * 64;
    const float* ar = agg + (size_t)row * 64;

    const float4* bj = (const float4*)(bl + jc);
    float4 A0 = bj[0], A1 = bj[1], A2 = bj[2], A3 = bj[3];

    #pragma unroll
    for (int kb = 0; kb < 64; kb += 4) {
        float4 iv = *(const float4*)(xr + kb);
        FMA4R(iv.x, Wl + (kb + 0) * 64 + jc, A0, A1, A2, A3);
        FMA4R(iv.y, Wl + (kb + 1) * 64 + jc, A0, A1, A2, A3);
        FMA4R(iv.z, Wl + (kb + 2) * 64 + jc, A0, A1, A2, A3);
        FMA4R(iv.w, Wl + (kb + 3) * 64 + jc, A0, A1, A2, A3);
    }
    #pragma unroll
    for (int kb = 0; kb < 64; kb += 4) {
        float4 iv = *(const float4*)(ar + kb);
        FMA4R(iv.x, Wl + (64 + kb + 0) * 64 + jc, A0, A1, A2, A3);
        FMA4R(iv.y, Wl + (64 + kb + 1) * 64 + jc, A0, A1, A2, A3);
        FMA4R(iv.z, Wl + (64 + kb + 2) * 64 + jc, A0, A1, A2, A3);
        FMA4R(iv.w, Wl + (64 + kb + 3) * 64 + jc, A0, A1, A2, A3);
    }

    // LayerNorm stats across the 4-lane group (each holds 16 of 64)
    float ls = SUM4(A0) + SUM4(A1) + SUM4(A2) + SUM4(A3);
    ls += __shfl_xor(ls, 1);
    ls += __shfl_xor(ls, 2);
    float m = ls * (1.0f / 64.0f);
    float vs = 0.f;
    VAR4(A0); VAR4(A1); VAR4(A2); VAR4(A3);
    vs += __shfl_xor(vs, 1);
    vs += __shfl_xor(vs, 2);
    float inv = rsqrtf(vs * (1.0f / 64.0f) + 1e-5f);

    float* xw = x + (size_t)row * 64 + jc;
    const float4* gg4 = (const float4*)(gl + jc);
    const float4* bb4 = (const float4*)(bel + jc);
    const float4* xv4 = (const float4*)(xr + jc);
    #define OUTC(Aj, c) do {                                                  \
        float4 xv = xv4[c]; float4 gg = gg4[c]; float4 bb = bb4[c];           \
        float4 y;                                                             \
        y.x = fmaxf((Aj.x - m) * inv * gg.x + bb.x, 0.f) + xv.x;              \
        y.y = fmaxf((Aj.y - m) * inv * gg.y + bb.y, 0.f) + xv.y;              \
        y.z = fmaxf((Aj.z - m) * inv * gg.z + bb.z, 0.f) + xv.z;              \
        y.w = fmaxf((Aj.w - m) * inv * gg.w + bb.w, 0.f) + xv.w;              \
        ((float4*)xw)[c] = y; } while (0)
    OUTC(A0, 0); OUTC(A1, 1); OUTC(A2, 2); OUTC(A3, 3);
    #undef OUTC
}

// ---- fusion: one THREAD per row (round-5 layout, known-good) ----
__global__ __launch_bounds__(256) void k_fuse(
    const float* __restrict__ W1, const float* __restrict__ b1,
    const float* __restrict__ W2, const float* __restrict__ b2,
    float* __restrict__ out, const float* __restrict__ z, int N, int rows)
{
    __shared__ float W1l[128 * 64];
    __shared__ float W2l[64 * 64];
    __shared__ float b1l[64], b2l[64];
    int tid = threadIdx.x;
    {
        const float4* Wa = (const float4*)W1;
        float4* Wla = (float4*)W1l;
        #pragma unroll
        for (int i = 0; i < 8; ++i) Wla[tid + i * 256] = Wa[tid + i * 256];
        const float4* Wb = (const float4*)W2;
        float4* Wlb = (float4*)W2l;
        #pragma unroll
        for (int i = 0; i < 4; ++i) Wlb[tid + i * 256] = Wb[tid + i * 256];
        if (tid < 64) { b1l[tid] = b1[tid]; b2l[tid] = b2[tid]; }
    }
    __syncthreads();

    int row = blockIdx.x * 256 + tid;
    if (row >= rows) return;
    int n = row % N;
    const float* hr = out + (size_t)row * 64;
    const float* zr = z + (size_t)n * 64;

    const float4* b1l4 = (const float4*)b1l;
    float4 A0 = b1l4[0],  A1 = b1l4[1],  A2 = b1l4[2],  A3 = b1l4[3];
    float4 A4 = b1l4[4],  A5 = b1l4[5],  A6 = b1l4[6],  A7 = b1l4[7];
    float4 A8 = b1l4[8],  A9 = b1l4[9],  A10 = b1l4[10], A11 = b1l4[11];
    float4 A12 = b1l4[12], A13 = b1l4[13], A14 = b1l4[14], A15 = b1l4[15];

    #pragma unroll
    for (int kc = 0; kc < 64; kc += 4) {
        float4 iv = *(const float4*)(hr + kc);
        FMA16(iv.x, W1l + (kc + 0) * 64);
        FMA16(iv.y, W1l + (kc + 1) * 64);
        FMA16(iv.z, W1l + (kc + 2) * 64);
        FMA16(iv.w, W1l + (kc + 3) * 64);
    }
    #pragma unroll
    for (int kc = 0; kc < 64; kc += 4) {
        float4 iv = *(const float4*)(zr + kc);
        FMA16(iv.x, W1l + (64 + kc + 0) * 64);
        FMA16(iv.y, W1l + (64 + kc + 1) * 64);
        FMA16(iv.z, W1l + (64 + kc + 2) * 64);
        FMA16(iv.w, W1l + (64 + kc + 3) * 64);
    }
    #define RELU4(Ai) do { Ai.x = fmaxf(Ai.x, 0.f); Ai.y = fmaxf(Ai.y, 0.f); \
                           Ai.z = fmaxf(Ai.z, 0.f); Ai.w = fmaxf(Ai.w, 0.f); } while (0)
    RELU4(A0);  RELU4(A1);  RELU4(A2);  RELU4(A3);
    RELU4(A4);  RELU4(A5);  RELU4(A6);  RELU4(A7);
    RELU4(A8);  RELU4(A9);  RELU4(A10); RELU4(A11);
    RELU4(A12); RELU4(A13); RELU4(A14); RELU4(A15);
    #undef RELU4

    float* ow = out + (size_t)row * 64;
    #pragma unroll
    for (int jc = 0; jc < 64; jc += 16) {
        const float4* bb4 = (const float4*)(b2l + jc);
        float4 O0 = bb4[0], O1 = bb4[1], O2 = bb4[2], O3 = bb4[3];
        #define KS(Ai, kb) do {                                               \
            FMA4R(Ai.x, W2l + (kb + 0) * 64 + jc, O0, O1, O2, O3);            \
            FMA4R(Ai.y, W2l + (kb + 1) * 64 + jc, O0, O1, O2, O3);            \
            FMA4R(Ai.z, W2l + (kb + 2) * 64 + jc, O0, O1, O2, O3);            \
            FMA4R(Ai.w, W2l + (kb + 3) * 64 + jc, O0, O1, O2, O3); } while (0)
        KS(A0, 0);   KS(A1, 4);   KS(A2, 8);   KS(A3, 12);
        KS(A4, 16);  KS(A5, 20);  KS(A6, 24);  KS(A7, 28);
        KS(A8, 32);  KS(A9, 36);  KS(A10, 40); KS(A11, 44);
        KS(A12, 48); KS(A13, 52); KS(A14, 56); KS(A15, 60);
        #undef KS
        float4* ow4 = (float4*)(ow + jc);
        ow4[0] = O0; ow4[1] = O1; ow4[2] = O2; ow4[3] = O3;
    }
}

extern "C" void kernel_launch(void* const* d_in, const int* in_sizes, int n_in,
                              void* d_out, int out_size, void* d_ws, size_t ws_size,
                              hipStream_t stream)
{
    const float* rel_text_init = (const float*)d_in[0];
    const float* struct_rel    = (const float*)d_in[1];
    const float* struct_W      = (const float*)d_in[2];
    const float* struct_b      = (const float*)d_in[3];
    const float* struct_g      = (const float*)d_in[4];
    const float* struct_beta   = (const float*)d_in[5];
    const float* text_rel      = (const float*)d_in[6];
    const float* text_W        = (const float*)d_in[7];
    const float* text_b        = (const float*)d_in[8];
    const float* text_g        = (const float*)d_in[9];
    const float* text_beta     = (const float*)d_in[10];
    const float* fuse_W1       = (const float*)d_in[11];
    const float* fuse_b1       = (const float*)d_in[12];
    const float* fuse_W2       = (const float*)d_in[13];
    const float* fuse_b2       = (const float*)d_in[14];
    const int*   h_index       = (const int*)d_in[15];
    const int*   edge_index    = (const int*)d_in[16];
    const int*   edge_type     = (const int*)d_in[17];
    const int*   text_edge_idx = (const int*)d_in[18];

    const int B  = in_sizes[15];
    const int N  = in_sizes[0] / 64;
    const int E  = in_sizes[17];
    const int ET = in_sizes[18] / 2;
    const int L  = in_sizes[3] / 64;
    const int R  = in_sizes[1] / (L * 64);

    const int* src  = edge_index;
    const int* dst  = edge_index + E;
    const int* tsrc = text_edge_idx;
    const int* tdst = text_edge_idx + ET;

    // ---- workspace layout ----
    float* x_t   = (float*)d_ws;                     // [N,64]
    float* agg_t = x_t + (size_t)N * 64;             // [N,64]
    float* agg_s = agg_t + (size_t)N * 64;           // [B,N,64]
    int*   cnt_s = (int*)(agg_s + (size_t)B * N * 64);  // [N]
    int*   off_s = cnt_s + N;                        // [N+1]
    int*   pk_s  = off_s + N + 1;                    // [E]
    int*   cnt_t = pk_s + E;                         // [N]
    int*   off_t = cnt_t + N;                        // [N+1]
    int*   pk_t  = off_t + N + 1;                    // [ET]

    float* x_s = (float*)d_out;                      // [B,N,64]

    const size_t nd  = (size_t)N * 64;
    const int rows_s = B * N;
    const int tot_s  = rows_s * 64;

    const int gb_init   = (tot_s + 255) / 256;
    const int gb_e      = (E + 255) / 256;
    const int gb_et     = (ET + 255) / 256;
    const int gb_wave_n = (N * 64 + 255) / 256;        // one wave per node
    const int gb_upd_s  = (rows_s * 4 + 255) / 256;    // 4 threads per row
    const int gb_upd_t  = (N * 4 + 255) / 256;
    const int gb_fuse   = (rows_s + 255) / 256;

    // ---- CSR builds ----
    hipMemsetAsync(cnt_s, 0, (size_t)N * 4, stream);
    hipMemsetAsync(cnt_t, 0, (size_t)N * 4, stream);
    k_hist<<<gb_e, 256, 0, stream>>>(dst, cnt_s, E);
    k_hist<<<gb_et, 256, 0, stream>>>(tdst, cnt_t, ET);
    k_scan<<<1, 1024, 0, stream>>>(cnt_s, off_s, N);
    k_scan<<<1, 1024, 0, stream>>>(cnt_t, off_t, N);
    k_fill<<<gb_e, 256, 0, stream>>>(src, dst, edge_type, off_s, cnt_s, pk_s, E);
    k_fill<<<gb_et, 256, 0, stream>>>(tsrc, tdst, nullptr, off_t, cnt_t, pk_t, ET);

    // ---- struct branch (state in d_out) ----
    k_init_onehot<<<gb_init, 256, 0, stream>>>(x_s, h_index, N, tot_s);
    for (int i = 0; i < L; ++i) {
        if (B == 2) {
            k_gather_struct2<<<gb_wave_n, 256, 0, stream>>>(
                x_s, agg_s, off_s, pk_s,
                struct_rel + (size_t)i * R * 64, h_index, N);
        } else {
            k_gather_struct_gen<<<(rows_s * 64 + 255) / 256, 256, 0, stream>>>(
                x_s, agg_s, off_s, pk_s,
                struct_rel + (size_t)i * R * 64, h_index, N, rows_s);
        }
        k_update<<<gb_upd_s, 256, 0, stream>>>(
            struct_W + (size_t)i * 128 * 64, struct_b + i * 64,
            struct_g + i * 64, struct_beta + i * 64, x_s, agg_s, rows_s);
    }

    // ---- text branch (batch-invariant) ----
    hipMemcpyAsync(x_t, rel_text_init, nd * sizeof(float),
                   hipMemcpyDeviceToDevice, stream);
    for (int i = 0; i < L; ++i) {
        k_gather_text<<<gb_wave_n, 256, 0, stream>>>(
            x_t, agg_t, off_t, pk_t,
            text_rel + (size_t)i * 64, rel_text_init, N);
        k_update<<<gb_upd_t, 256, 0, stream>>>(
            text_W + (size_t)i * 128 * 64, text_b + i * 64,
            text_g + i * 64, text_beta + i * 64, x_t, agg_t, N);
    }

    // ---- fusion ----
    k_fuse<<<gb_fuse, 256, 0, stream>>>(
        fuse_W1, fuse_b1, fuse_W2, fuse_b2, x_s, x_t, N, rows_s);
}

// Round 7
// 800.232 us; speedup vs baseline: 9.1468x; 1.0793x over previous
//
#include <hip/hip_runtime.h>

// ---------------------------------------------------------------------------
// SemmaRelModel: two 6-layer NBFNet branches + MLP fusion.
// Round 7:
//  - k_fuse: 4 threads/row + 4-step shfl rotation for 2nd GEMV (round-6 had
//    VGPR=84 partial spill, WRITE 76MB vs 26MB logical, 1.5 waves/SIMD).
//  - gathers: wave-coalesced packed[] load + __shfl broadcast (kills the
//    scalar-load -> vector-load dependency chain per edge).
//  - k_scan: single-block loop -> 3-kernel multi-block scan.
// ---------------------------------------------------------------------------

// ---- macro kit ----
#define FMA4R(v, wbase, R0, R1, R2, R3) do {                                  \
    const float4* _w = (const float4*)(wbase); float4 _t;                     \
    _t=_w[0]; R0.x=fmaf(v,_t.x,R0.x); R0.y=fmaf(v,_t.y,R0.y); R0.z=fmaf(v,_t.z,R0.z); R0.w=fmaf(v,_t.w,R0.w); \
    _t=_w[1]; R1.x=fmaf(v,_t.x,R1.x); R1.y=fmaf(v,_t.y,R1.y); R1.z=fmaf(v,_t.z,R1.z); R1.w=fmaf(v,_t.w,R1.w); \
    _t=_w[2]; R2.x=fmaf(v,_t.x,R2.x); R2.y=fmaf(v,_t.y,R2.y); R2.z=fmaf(v,_t.z,R2.z); R2.w=fmaf(v,_t.w,R2.w); \
    _t=_w[3]; R3.x=fmaf(v,_t.x,R3.x); R3.y=fmaf(v,_t.y,R3.y); R3.z=fmaf(v,_t.z,R3.z); R3.w=fmaf(v,_t.w,R3.w); \
} while (0)

#define SUM4(Ai) ((Ai.x + Ai.y) + (Ai.z + Ai.w))
#define VAR4(Ai) do { float _c;                                               \
    _c = Ai.x - m; vs = fmaf(_c, _c, vs); _c = Ai.y - m; vs = fmaf(_c, _c, vs); \
    _c = Ai.z - m; vs = fmaf(_c, _c, vs); _c = Ai.w - m; vs = fmaf(_c, _c, vs); \
} while (0)

#define RSEL(ty) (((ty) < 2) ? ((ty) == 0 ? r0 : r1) : ((ty) == 2 ? r2 : r3))

// x[idx] = (n == h_index[b]) ? 1 : 0   over [B,N,64]
__global__ __launch_bounds__(256) void k_init_onehot(
    float* __restrict__ x, const int* __restrict__ h_index, int N, int total)
{
    int idx = blockIdx.x * 256 + threadIdx.x;
    if (idx >= total) return;
    int row = idx >> 6;
    int b = row / N;
    int n = row - b * N;
    x[idx] = (n == h_index[b]) ? 1.0f : 0.0f;
}

// ---- CSR build ----
__global__ __launch_bounds__(256) void k_hist(
    const int* __restrict__ dst, int* __restrict__ cnt, int E)
{
    int e = blockIdx.x * 256 + threadIdx.x;
    if (e < E) atomicAdd(&cnt[dst[e]], 1);
}

// block-local inclusive scan: off[i+1] = local_incl(i); bsum[blk] = block total
__global__ __launch_bounds__(1024) void k_scan_blk(
    const int* __restrict__ cnt, int* __restrict__ off,
    int* __restrict__ bsum, int n)
{
    __shared__ int wsum[16], wpre[16], tot;
    int tid = threadIdx.x, lane = tid & 63, w = tid >> 6;
    int i = blockIdx.x * 1024 + tid;
    int v = (i < n) ? cnt[i] : 0;
    int s = v;
    #pragma unroll
    for (int d = 1; d < 64; d <<= 1) {
        int t = __shfl_up(s, d);
        if (lane >= d) s += t;
    }
    if (lane == 63) wsum[w] = s;
    __syncthreads();
    if (w == 0 && lane < 16) {
        int ws = wsum[lane];
        int p = ws;
        #pragma unroll
        for (int d = 1; d < 16; d <<= 1) {
            int t = __shfl_up(p, d);
            if (lane >= d) p += t;
        }
        wpre[lane] = p - ws;
        if (lane == 15) tot = p;
    }
    __syncthreads();
    if (i < n) off[i + 1] = wpre[w] + s;
    if (tid == 0) {
        bsum[blockIdx.x] = tot;
        if (blockIdx.x == 0) off[0] = 0;
    }
}

// exclusive scan of block sums in place (nb <= 1024)
__global__ __launch_bounds__(1024) void k_scan_top(int* __restrict__ bsum, int nb)
{
    __shared__ int wsum[16], wpre[16];
    int tid = threadIdx.x, lane = tid & 63, w = tid >> 6;
    int v = (tid < nb) ? bsum[tid] : 0;
    int s = v;
    #pragma unroll
    for (int d = 1; d < 64; d <<= 1) {
        int t = __shfl_up(s, d);
        if (lane >= d) s += t;
    }
    if (lane == 63) wsum[w] = s;
    __syncthreads();
    if (w == 0 && lane < 16) {
        int ws = wsum[lane];
        int p = ws;
        #pragma unroll
        for (int d = 1; d < 16; d <<= 1) {
            int t = __shfl_up(p, d);
            if (lane >= d) p += t;
        }
        wpre[lane] = p - ws;
    }
    __syncthreads();
    if (tid < nb) bsum[tid] = wpre[w] + s - v;   // exclusive
}

__global__ __launch_bounds__(1024) void k_scan_add(
    const int* __restrict__ bsum, int* __restrict__ off, int n)
{
    int i = blockIdx.x * 1024 + threadIdx.x;
    if (i < n) off[i + 1] += bsum[blockIdx.x];
}

__global__ __launch_bounds__(256) void k_fill(
    const int* __restrict__ src, const int* __restrict__ dst,
    const int* __restrict__ etype,
    const int* __restrict__ off, int* __restrict__ cnt,
    int* __restrict__ packed, int E)
{
    int e = blockIdx.x * 256 + threadIdx.x;
    if (e >= E) return;
    int d = dst[e];
    int pos = off[d] + atomicSub(&cnt[d], 1) - 1;
    int ty = etype ? etype[e] : 0;
    packed[pos] = src[e] | (ty << 27);
}

// ---- struct aggregation: one wave per node, BOTH batches; packed[] loaded
// coalesced per wave and broadcast by __shfl (addresses register-resident).
__global__ __launch_bounds__(256) void k_gather_struct2(
    const float* __restrict__ x, float* __restrict__ agg,
    const int* __restrict__ off, const int* __restrict__ packed,
    const float* __restrict__ rel,       // [4,64]
    const int* __restrict__ h_index,
    int N)
{
    int n = (blockIdx.x * 256 + threadIdx.x) >> 6;
    int lane = threadIdx.x & 63;
    if (n >= N) return;
    float r0 = rel[lane], r1 = rel[64 + lane];
    float r2 = rel[128 + lane], r3 = rel[192 + lane];
    const float* x0 = x;
    const float* x1 = x + (size_t)N * 64;
    float acc0 = (n == h_index[0]) ? 1.0f : 0.0f;
    float acc1 = (n == h_index[1]) ? 1.0f : 0.0f;
    int p0 = __builtin_amdgcn_readfirstlane(off[n]);
    int p1 = __builtin_amdgcn_readfirstlane(off[n + 1]);
    for (int p = p0; p < p1; p += 64) {
        int myPk = (p + lane < p1) ? packed[p + lane] : 0;   // coalesced
        int cnt = min(p1 - p, 64);
        int i = 0;
        for (; i + 4 <= cnt; i += 4) {
            int pka = __shfl(myPk, i + 0), pkb = __shfl(myPk, i + 1);
            int pkc = __shfl(myPk, i + 2), pkd = __shfl(myPk, i + 3);
            int sa = pka & 0x03FFFFFF, ta = pka >> 27;
            int sb = pkb & 0x03FFFFFF, tb = pkb >> 27;
            int sc = pkc & 0x03FFFFFF, tc = pkc >> 27;
            int sd = pkd & 0x03FFFFFF, td = pkd >> 27;
            float ra = RSEL(ta), rb = RSEL(tb), rc = RSEL(tc), rd = RSEL(td);
            float a0 = x0[(size_t)sa * 64 + lane], a1 = x1[(size_t)sa * 64 + lane];
            float b0 = x0[(size_t)sb * 64 + lane], b1 = x1[(size_t)sb * 64 + lane];
            float c0 = x0[(size_t)sc * 64 + lane], c1 = x1[(size_t)sc * 64 + lane];
            float d0 = x0[(size_t)sd * 64 + lane], d1 = x1[(size_t)sd * 64 + lane];
            acc0 = fmaf(a0, ra, acc0); acc1 = fmaf(a1, ra, acc1);
            acc0 = fmaf(b0, rb, acc0); acc1 = fmaf(b1, rb, acc1);
            acc0 = fmaf(c0, rc, acc0); acc1 = fmaf(c1, rc, acc1);
            acc0 = fmaf(d0, rd, acc0); acc1 = fmaf(d1, rd, acc1);
        }
        for (; i < cnt; ++i) {
            int pk = __shfl(myPk, i);
            int s = pk & 0x03FFFFFF, ty = pk >> 27;
            float r = RSEL(ty);
            acc0 = fmaf(x0[(size_t)s * 64 + lane], r, acc0);
            acc1 = fmaf(x1[(size_t)s * 64 + lane], r, acc1);
        }
    }
    agg[(size_t)n * 64 + lane] = acc0;
    agg[(size_t)(N + n) * 64 + lane] = acc1;
}

// generic fallback (B != 2)
__global__ __launch_bounds__(256) void k_gather_struct_gen(
    const float* __restrict__ x, float* __restrict__ agg,
    const int* __restrict__ off, const int* __restrict__ packed,
    const float* __restrict__ rel, const int* __restrict__ h_index,
    int N, int BN)
{
    int wid = (blockIdx.x * 256 + threadIdx.x) >> 6;
    int lane = threadIdx.x & 63;
    if (wid >= BN) return;
    int b = wid / N;
    int n = wid - b * N;
    float r0 = rel[lane], r1 = rel[64 + lane];
    float r2 = rel[128 + lane], r3 = rel[192 + lane];
    const float* xb = x + (size_t)b * N * 64;
    float acc = (n == h_index[b]) ? 1.0f : 0.0f;
    int p0 = off[n], p1 = off[n + 1];
    for (int p = p0; p < p1; ++p) {
        int pk = packed[p];
        int s = pk & 0x03FFFFFF, ty = pk >> 27;
        acc = fmaf(xb[(size_t)s * 64 + lane], RSEL(ty), acc);
    }
    agg[(size_t)wid * 64 + lane] = acc;
}

// ---- text aggregation: one wave per node, shfl-broadcast edges ----
__global__ __launch_bounds__(256) void k_gather_text(
    const float* __restrict__ x, float* __restrict__ agg,
    const int* __restrict__ off, const int* __restrict__ packed,
    const float* __restrict__ rel,       // [64]
    const float* __restrict__ init,      // [N,64]
    int N)
{
    int n = (blockIdx.x * 256 + threadIdx.x) >> 6;
    int lane = threadIdx.x & 63;
    if (n >= N) return;
    float r = rel[lane];
    float acc = init[(size_t)n * 64 + lane];
    float acc2 = 0.f;
    int p0 = __builtin_amdgcn_readfirstlane(off[n]);
    int p1 = __builtin_amdgcn_readfirstlane(off[n + 1]);
    for (int p = p0; p < p1; p += 64) {
        int myPk = (p + lane < p1) ? packed[p + lane] : 0;
        int cnt = min(p1 - p, 64);
        int i = 0;
        for (; i + 4 <= cnt; i += 4) {
            int sa = __shfl(myPk, i + 0), sb = __shfl(myPk, i + 1);
            int sc = __shfl(myPk, i + 2), sd = __shfl(myPk, i + 3);
            float a = x[(size_t)sa * 64 + lane];
            float b = x[(size_t)sb * 64 + lane];
            float c = x[(size_t)sc * 64 + lane];
            float d = x[(size_t)sd * 64 + lane];
            acc = fmaf(a, r, acc);  acc2 = fmaf(b, r, acc2);
            acc = fmaf(c, r, acc);  acc2 = fmaf(d, r, acc2);
        }
        for (; i < cnt; ++i) {
            int s = __shfl(myPk, i);
            acc = fmaf(x[(size_t)s * 64 + lane], r, acc);
        }
    }
    agg[(size_t)n * 64 + lane] = acc + acc2;
}

// ---- dense update: 4 threads per row, 16 outputs each ----
__global__ __launch_bounds__(256) void k_update(
    const float* __restrict__ W,      // [128,64]
    const float* __restrict__ bias, const float* __restrict__ g,
    const float* __restrict__ beta,
    float* __restrict__ x, const float* __restrict__ agg, int rows)
{
    __shared__ float Wl[128 * 64];
    __shared__ float bl[64], gl[64], bel[64];
    int tid = threadIdx.x;
    {
        const float4* W4 = (const float4*)W;
        float4* Wl4 = (float4*)Wl;
        #pragma unroll
        for (int i = 0; i < 8; ++i) Wl4[tid + i * 256] = W4[tid + i * 256];
        if (tid < 64) { bl[tid] = bias[tid]; gl[tid] = g[tid]; bel[tid] = beta[tid]; }
    }
    __syncthreads();

    int gt = blockIdx.x * 256 + tid;
    int row = gt >> 2;
    int jc = (gt & 3) * 16;
    if (row >= rows) return;
    const float* xr = x + (size_t)row * 64;
    const float* ar = agg + (size_t)row * 64;

    const float4* bj = (const float4*)(bl + jc);
    float4 A0 = bj[0], A1 = bj[1], A2 = bj[2], A3 = bj[3];

    #pragma unroll
    for (int kb = 0; kb < 64; kb += 4) {
        float4 iv = *(const float4*)(xr + kb);
        FMA4R(iv.x, Wl + (kb + 0) * 64 + jc, A0, A1, A2, A3);
        FMA4R(iv.y, Wl + (kb + 1) * 64 + jc, A0, A1, A2, A3);
        FMA4R(iv.z, Wl + (kb + 2) * 64 + jc, A0, A1, A2, A3);
        FMA4R(iv.w, Wl + (kb + 3) * 64 + jc, A0, A1, A2, A3);
    }
    #pragma unroll
    for (int kb = 0; kb < 64; kb += 4) {
        float4 iv = *(const float4*)(ar + kb);
        FMA4R(iv.x, Wl + (64 + kb + 0) * 64 + jc, A0, A1, A2, A3);
        FMA4R(iv.y, Wl + (64 + kb + 1) * 64 + jc, A0, A1, A2, A3);
        FMA4R(iv.z, Wl + (64 + kb + 2) * 64 + jc, A0, A1, A2, A3);
        FMA4R(iv.w, Wl + (64 + kb + 3) * 64 + jc, A0, A1, A2, A3);
    }

    float ls = SUM4(A0) + SUM4(A1) + SUM4(A2) + SUM4(A3);
    ls += __shfl_xor(ls, 1);
    ls += __shfl_xor(ls, 2);
    float m = ls * (1.0f / 64.0f);
    float vs = 0.f;
    VAR4(A0); VAR4(A1); VAR4(A2); VAR4(A3);
    vs += __shfl_xor(vs, 1);
    vs += __shfl_xor(vs, 2);
    float inv = rsqrtf(vs * (1.0f / 64.0f) + 1e-5f);

    float* xw = x + (size_t)row * 64 + jc;
    const float4* gg4 = (const float4*)(gl + jc);
    const float4* bb4 = (const float4*)(bel + jc);
    const float4* xv4 = (const float4*)(xr + jc);
    #define OUTC(Aj, c) do {                                                  \
        float4 xv = xv4[c]; float4 gg = gg4[c]; float4 bb = bb4[c];           \
        float4 y;                                                             \
        y.x = fmaxf((Aj.x - m) * inv * gg.x + bb.x, 0.f) + xv.x;              \
        y.y = fmaxf((Aj.y - m) * inv * gg.y + bb.y, 0.f) + xv.y;              \
        y.z = fmaxf((Aj.z - m) * inv * gg.z + bb.z, 0.f) + xv.z;              \
        y.w = fmaxf((Aj.w - m) * inv * gg.w + bb.w, 0.f) + xv.w;              \
        ((float4*)xw)[c] = y; } while (0)
    OUTC(A0, 0); OUTC(A1, 1); OUTC(A2, 2); OUTC(A3, 3);
    #undef OUTC
}

// ---- fusion: 4 threads/row; 2nd GEMV via 4-step shfl rotation ----
// out_row = relu(concat(h_row, z_row) @ W1 + b1) @ W2 + b2  (in place on out=h)
__global__ __launch_bounds__(256) void k_fuse(
    const float* __restrict__ W1, const float* __restrict__ b1,
    const float* __restrict__ W2, const float* __restrict__ b2,
    float* __restrict__ out, const float* __restrict__ z, int N, int rows)
{
    __shared__ float W1l[128 * 64];
    __shared__ float W2l[64 * 64];
    __shared__ float b1l[64], b2l[64];
    int tid = threadIdx.x;
    {
        const float4* Wa = (const float4*)W1;
        float4* Wla = (float4*)W1l;
        #pragma unroll
        for (int i = 0; i < 8; ++i) Wla[tid + i * 256] = Wa[tid + i * 256];
        const float4* Wb = (const float4*)W2;
        float4* Wlb = (float4*)W2l;
        #pragma unroll
        for (int i = 0; i < 4; ++i) Wlb[tid + i * 256] = Wb[tid + i * 256];
        if (tid < 64) { b1l[tid] = b1[tid]; b2l[tid] = b2[tid]; }
    }
    __syncthreads();

    int gt = blockIdx.x * 256 + tid;
    int row = gt >> 2;
    int q = gt & 3;
    int jc = q * 16;
    if (row >= rows) return;
    int n = row % N;
    const float* hr = out + (size_t)row * 64;
    const float* zr = z + (size_t)n * 64;
    int lane = tid & 63;

    // first GEMV: F = relu(concat(h,z) @ W1 + b1), 16 outputs (chunk jc)
    const float4* bj = (const float4*)(b1l + jc);
    float4 F0 = bj[0], F1 = bj[1], F2 = bj[2], F3 = bj[3];
    #pragma unroll
    for (int kb = 0; kb < 64; kb += 4) {
        float4 iv = *(const float4*)(hr + kb);
        FMA4R(iv.x, W1l + (kb + 0) * 64 + jc, F0, F1, F2, F3);
        FMA4R(iv.y, W1l + (kb + 1) * 64 + jc, F0, F1, F2, F3);
        FMA4R(iv.z, W1l + (kb + 2) * 64 + jc, F0, F1, F2, F3);
        FMA4R(iv.w, W1l + (kb + 3) * 64 + jc, F0, F1, F2, F3);
    }
    #pragma unroll
    for (int kb = 0; kb < 64; kb += 4) {
        float4 iv = *(const float4*)(zr + kb);
        FMA4R(iv.x, W1l + (64 + kb + 0) * 64 + jc, F0, F1, F2, F3);
        FMA4R(iv.y, W1l + (64 + kb + 1) * 64 + jc, F0, F1, F2, F3);
        FMA4R(iv.z, W1l + (64 + kb + 2) * 64 + jc, F0, F1, F2, F3);
        FMA4R(iv.w, W1l + (64 + kb + 3) * 64 + jc, F0, F1, F2, F3);
    }
    F0.x = fmaxf(F0.x, 0.f); F0.y = fmaxf(F0.y, 0.f); F0.z = fmaxf(F0.z, 0.f); F0.w = fmaxf(F0.w, 0.f);
    F1.x = fmaxf(F1.x, 0.f); F1.y = fmaxf(F1.y, 0.f); F1.z = fmaxf(F1.z, 0.f); F1.w = fmaxf(F1.w, 0.f);
    F2.x = fmaxf(F2.x, 0.f); F2.y = fmaxf(F2.y, 0.f); F2.z = fmaxf(F2.z, 0.f); F2.w = fmaxf(F2.w, 0.f);
    F3.x = fmaxf(F3.x, 0.f); F3.y = fmaxf(F3.y, 0.f); F3.z = fmaxf(F3.z, 0.f); F3.w = fmaxf(F3.w, 0.f);

    // second GEMV: O[jc..jc+16) = sum_k f[k] * W2[k][jc..]; f-chunks rotate
    // around the 4-lane group (thread q starts holding chunk q).
    const float4* bj2 = (const float4*)(b2l + jc);
    float4 O0 = bj2[0], O1 = bj2[1], O2 = bj2[2], O3 = bj2[3];
    int srcLane = (lane & ~3) | ((q + 1) & 3);
    #pragma unroll
    for (int s = 0; s < 4; ++s) {
        int c = (q + s) & 3;                    // chunk currently held
        const float* w2 = W2l + (c * 16) * 64 + jc;
        FMA4R(F0.x, w2 + 0 * 64,  O0, O1, O2, O3);
        FMA4R(F0.y, w2 + 1 * 64,  O0, O1, O2, O3);
        FMA4R(F0.z, w2 + 2 * 64,  O0, O1, O2, O3);
        FMA4R(F0.w, w2 + 3 * 64,  O0, O1, O2, O3);
        FMA4R(F1.x, w2 + 4 * 64,  O0, O1, O2, O3);
        FMA4R(F1.y, w2 + 5 * 64,  O0, O1, O2, O3);
        FMA4R(F1.z, w2 + 6 * 64,  O0, O1, O2, O3);
        FMA4R(F1.w, w2 + 7 * 64,  O0, O1, O2, O3);
        FMA4R(F2.x, w2 + 8 * 64,  O0, O1, O2, O3);
        FMA4R(F2.y, w2 + 9 * 64,  O0, O1, O2, O3);
        FMA4R(F2.z, w2 + 10 * 64, O0, O1, O2, O3);
        FMA4R(F2.w, w2 + 11 * 64, O0, O1, O2, O3);
        FMA4R(F3.x, w2 + 12 * 64, O0, O1, O2, O3);
        FMA4R(F3.y, w2 + 13 * 64, O0, O1, O2, O3);
        FMA4R(F3.z, w2 + 14 * 64, O0, O1, O2, O3);
        FMA4R(F3.w, w2 + 15 * 64, O0, O1, O2, O3);
        if (s < 3) {
            F0.x = __shfl(F0.x, srcLane); F0.y = __shfl(F0.y, srcLane);
            F0.z = __shfl(F0.z, srcLane); F0.w = __shfl(F0.w, srcLane);
            F1.x = __shfl(F1.x, srcLane); F1.y = __shfl(F1.y, srcLane);
            F1.z = __shfl(F1.z, srcLane); F1.w = __shfl(F1.w, srcLane);
            F2.x = __shfl(F2.x, srcLane); F2.y = __shfl(F2.y, srcLane);
            F2.z = __shfl(F2.z, srcLane); F2.w = __shfl(F2.w, srcLane);
            F3.x = __shfl(F3.x, srcLane); F3.y = __shfl(F3.y, srcLane);
            F3.z = __shfl(F3.z, srcLane); F3.w = __shfl(F3.w, srcLane);
        }
    }
    float4* ow4 = (float4*)(out + (size_t)row * 64 + jc);
    ow4[0] = O0; ow4[1] = O1; ow4[2] = O2; ow4[3] = O3;
}

extern "C" void kernel_launch(void* const* d_in, const int* in_sizes, int n_in,
                              void* d_out, int out_size, void* d_ws, size_t ws_size,
                              hipStream_t stream)
{
    const float* rel_text_init = (const float*)d_in[0];
    const float* struct_rel    = (const float*)d_in[1];
    const float* struct_W      = (const float*)d_in[2];
    const float* struct_b      = (const float*)d_in[3];
    const float* struct_g      = (const float*)d_in[4];
    const float* struct_beta   = (const float*)d_in[5];
    const float* text_rel      = (const float*)d_in[6];
    const float* text_W        = (const float*)d_in[7];
    const float* text_b        = (const float*)d_in[8];
    const float* text_g        = (const float*)d_in[9];
    const float* text_beta     = (const float*)d_in[10];
    const float* fuse_W1       = (const float*)d_in[11];
    const float* fuse_b1       = (const float*)d_in[12];
    const float* fuse_W2       = (const float*)d_in[13];
    const float* fuse_b2       = (const float*)d_in[14];
    const int*   h_index       = (const int*)d_in[15];
    const int*   edge_index    = (const int*)d_in[16];
    const int*   edge_type     = (const int*)d_in[17];
    const int*   text_edge_idx = (const int*)d_in[18];

    const int B  = in_sizes[15];
    const int N  = in_sizes[0] / 64;
    const int E  = in_sizes[17];
    const int ET = in_sizes[18] / 2;
    const int L  = in_sizes[3] / 64;
    const int R  = in_sizes[1] / (L * 64);

    const int* src  = edge_index;
    const int* dst  = edge_index + E;
    const int* tsrc = text_edge_idx;
    const int* tdst = text_edge_idx + ET;

    // ---- workspace layout ----
    float* x_t   = (float*)d_ws;                     // [N,64]
    float* agg_t = x_t + (size_t)N * 64;             // [N,64]
    float* agg_s = agg_t + (size_t)N * 64;           // [B,N,64]
    int*   cnt_s = (int*)(agg_s + (size_t)B * N * 64);  // [N]
    int*   off_s = cnt_s + N;                        // [N+1]
    int*   pk_s  = off_s + N + 1;                    // [E]
    int*   cnt_t = pk_s + E;                         // [N]
    int*   off_t = cnt_t + N;                        // [N+1]
    int*   pk_t  = off_t + N + 1;                    // [ET]
    int*   bsum_s = pk_t + ET;                       // [<=1024]
    int*   bsum_t = bsum_s + 1024;                   // [<=1024]

    float* x_s = (float*)d_out;                      // [B,N,64]

    const size_t nd  = (size_t)N * 64;
    const int rows_s = B * N;
    const int tot_s  = rows_s * 64;
    const int nb     = (N + 1023) / 1024;

    const int gb_init   = (tot_s + 255) / 256;
    const int gb_e      = (E + 255) / 256;
    const int gb_et     = (ET + 255) / 256;
    const int gb_wave_n = (N * 64 + 255) / 256;        // one wave per node
    const int gb_upd_s  = (rows_s * 4 + 255) / 256;    // 4 threads per row
    const int gb_upd_t  = (N * 4 + 255) / 256;
    const int gb_fuse   = (rows_s * 4 + 255) / 256;

    // ---- CSR builds ----
    hipMemsetAsync(cnt_s, 0, (size_t)N * 4, stream);
    hipMemsetAsync(cnt_t, 0, (size_t)N * 4, stream);
    k_hist<<<gb_e, 256, 0, stream>>>(dst, cnt_s, E);
    k_hist<<<gb_et, 256, 0, stream>>>(tdst, cnt_t, ET);
    k_scan_blk<<<nb, 1024, 0, stream>>>(cnt_s, off_s, bsum_s, N);
    k_scan_blk<<<nb, 1024, 0, stream>>>(cnt_t, off_t, bsum_t, N);
    k_scan_top<<<1, 1024, 0, stream>>>(bsum_s, nb);
    k_scan_top<<<1, 1024, 0, stream>>>(bsum_t, nb);
    k_scan_add<<<nb, 1024, 0, stream>>>(bsum_s, off_s, N);
    k_scan_add<<<nb, 1024, 0, stream>>>(bsum_t, off_t, N);
    k_fill<<<gb_e, 256, 0, stream>>>(src, dst, edge_type, off_s, cnt_s, pk_s, E);
    k_fill<<<gb_et, 256, 0, stream>>>(tsrc, tdst, nullptr, off_t, cnt_t, pk_t, ET);

    // ---- struct branch (state in d_out) ----
    k_init_onehot<<<gb_init, 256, 0, stream>>>(x_s, h_index, N, tot_s);
    for (int i = 0; i < L; ++i) {
        if (B == 2) {
            k_gather_struct2<<<gb_wave_n, 256, 0, stream>>>(
                x_s, agg_s, off_s, pk_s,
                struct_rel + (size_t)i * R * 64, h_index, N);
        } else {
            k_gather_struct_gen<<<(rows_s * 64 + 255) / 256, 256, 0, stream>>>(
                x_s, agg_s, off_s, pk_s,
                struct_rel + (size_t)i * R * 64, h_index, N, rows_s);
        }
        k_update<<<gb_upd_s, 256, 0, stream>>>(
            struct_W + (size_t)i * 128 * 64, struct_b + i * 64,
            struct_g + i * 64, struct_beta + i * 64, x_s, agg_s, rows_s);
    }

    // ---- text branch (batch-invariant) ----
    hipMemcpyAsync(x_t, rel_text_init, nd * sizeof(float),
                   hipMemcpyDeviceToDevice, stream);
    for (int i = 0; i < L; ++i) {
        k_gather_text<<<gb_wave_n, 256, 0, stream>>>(
            x_t, agg_t, off_t, pk_t,
            text_rel + (size_t)i * 64, rel_text_init, N);
        k_update<<<gb_upd_t, 256, 0, stream>>>(
            text_W + (size_t)i * 128 * 64, text_b + i * 64,
            text_g + i * 64, text_beta + i * 64, x_t, agg_t, N);
    }

    // ---- fusion ----
    k_fuse<<<gb_fuse, 256, 0, stream>>>(
        fuse_W1, fuse_b1, fuse_W2, fuse_b2, x_s, x_t, N, rows_s);
}